// Round 2
// baseline (683.512 us; speedup 1.0000x reference)
//
#include <hip/hip_runtime.h>

#define NN 100000
#define NE 1600000
#define NTOT (NN + NE)

typedef __attribute__((ext_vector_type(8))) short bf16x8;
typedef __attribute__((ext_vector_type(4))) float f32x4;

__device__ __forceinline__ float bf2f(unsigned short u) {
  union { unsigned int i; float f; } v; v.i = ((unsigned int)u) << 16; return v.f;
}
__device__ __forceinline__ unsigned short f2bf(float f) {
  union { float f; unsigned int i; } v; v.f = f;
  unsigned int i = v.i;
  i += 0x7fffu + ((i >> 16) & 1u);
  return (unsigned short)(i >> 16);
}

// ---------------- CSR build ----------------
__global__ void k_init(int* __restrict__ deg) {
  int i = blockIdx.x * 256 + threadIdx.x;
  if (i < NN) deg[i] = 1;  // self-loop pre-counted
}

__global__ void k_hist(const int* __restrict__ ei, int* __restrict__ deg) {
  int e = blockIdx.x * 256 + threadIdx.x;
  if (e < NE) atomicAdd(&deg[ei[NE + e]], 1);
}

__global__ void k_scan(const int* __restrict__ deg, int* __restrict__ rowptr,
                       int* __restrict__ cursor) {
  __shared__ int wsum[16];
  __shared__ int carry_s;
  int tid = threadIdx.x, lane = tid & 63, wid = tid >> 6;
  if (tid == 0) carry_s = 0;
  __syncthreads();
  for (int base = 0; base < NN; base += 1024) {
    int i = base + tid;
    int v = (i < NN) ? deg[i] : 0;
    int x = v;
#pragma unroll
    for (int d = 1; d < 64; d <<= 1) {
      int y = __shfl_up(x, d, 64);
      if (lane >= d) x += y;
    }
    if (lane == 63) wsum[wid] = x;
    __syncthreads();
    int carry = carry_s;
    __syncthreads();
    if (tid < 16) {
      int t = wsum[tid];
      int xx = t;
#pragma unroll
      for (int d = 1; d < 16; d <<= 1) {
        int y = __shfl_up(xx, d, 16);
        if (tid >= d) xx += y;
      }
      wsum[tid] = xx - t;                      // exclusive wave offset
      if (tid == 15) carry_s = carry + xx;     // running total
    }
    __syncthreads();
    if (i < NN) {
      int excl = carry + wsum[wid] + (x - v);
      rowptr[i] = excl;
      cursor[i] = excl;
    }
  }
  __syncthreads();
  if (tid == 0) rowptr[NN] = carry_s;
}

__global__ void k_scatter(const int* __restrict__ ei, int* __restrict__ cursor,
                          int* __restrict__ col) {
  int t = blockIdx.x * 256 + threadIdx.x;
  if (t < NE) {
    int s = ei[t], d = ei[NE + t];
    col[atomicAdd(&cursor[d], 1)] = s;
  } else if (t < NTOT) {
    int nn = t - NE;
    col[atomicAdd(&cursor[nn], 1)] = nn;
  }
}

// ---------------- W1 hi/lo bf16 split (once) ----------------
__global__ void k_cvtW(const float* __restrict__ W1, unsigned short* __restrict__ Wh,
                       unsigned short* __restrict__ Wl) {
  int i = blockIdx.x * 256 + threadIdx.x;
  if (i < 128 * 128) {
    float v = W1[i];
    unsigned short h = f2bf(v);
    Wh[i] = h;
    Wl[i] = f2bf(v - bf2f(h));
  }
}

// ---------------- Layer 1 GEMM: h1 = x @ W1^T, fp32 via hi/lo split MFMA ----------------
__global__ __launch_bounds__(256) void k_gemm1(const float* __restrict__ x,
                                               const unsigned short* __restrict__ Wh,
                                               const unsigned short* __restrict__ Wl,
                                               float* __restrict__ h1) {
  int wid = threadIdx.x >> 6, lane = threadIdx.x & 63;
  int tile = blockIdx.x * 4 + wid;          // 16-node tile
  if (tile >= NN / 16) return;
  int r16 = lane & 15, quad = lane >> 4;
  // A fragments: row r16 of tile, k-chunks c*32 + quad*8 .. +7, hi/lo bf16 split
  const float* xrow = x + (size_t)(tile * 16 + r16) * 128 + quad * 8;
  bf16x8 ah[4], al[4];
#pragma unroll
  for (int c = 0; c < 4; ++c) {
#pragma unroll
    for (int j = 0; j < 8; ++j) {
      float v = xrow[c * 32 + j];
      unsigned short h = f2bf(v);
      ah[c][j] = (short)h;
      al[c][j] = (short)f2bf(v - bf2f(h));
    }
  }
#pragma unroll
  for (int ot = 0; ot < 8; ++ot) {
    const bf16x8* whrow = (const bf16x8*)(Wh + (size_t)(ot * 16 + r16) * 128);
    const bf16x8* wlrow = (const bf16x8*)(Wl + (size_t)(ot * 16 + r16) * 128);
    f32x4 acc = {0.f, 0.f, 0.f, 0.f};
#pragma unroll
    for (int c = 0; c < 4; ++c) {
      bf16x8 wh = whrow[c * 4 + quad];
      bf16x8 wl = wlrow[c * 4 + quad];
      acc = __builtin_amdgcn_mfma_f32_16x16x32_bf16(ah[c], wh, acc, 0, 0, 0);
      acc = __builtin_amdgcn_mfma_f32_16x16x32_bf16(ah[c], wl, acc, 0, 0, 0);
      acc = __builtin_amdgcn_mfma_f32_16x16x32_bf16(al[c], wh, acc, 0, 0, 0);
    }
    // D: col = lane&15, row = quad*4 + reg
    float* o = h1 + (size_t)(tile * 16 + quad * 4) * 128 + ot * 16 + r16;
    o[0] = acc[0]; o[128] = acc[1]; o[256] = acc[2]; o[384] = acc[3];
  }
}

// ---------------- attention coefficients layer 1 ----------------
__global__ void k_att1(const float* __restrict__ h1,
                       const float* __restrict__ asrc,
                       const float* __restrict__ adst,
                       float* __restrict__ as1, float* __restrict__ ad1) {
  int i = blockIdx.x * 256 + threadIdx.x;
  if (i >= NN * 4) return;
  int nn = i >> 2, h = i & 3;
  const float4* row = (const float4*)(h1 + (size_t)nn * 128 + h * 32);
  float s = 0.f, d = 0.f;
#pragma unroll
  for (int c4 = 0; c4 < 8; ++c4) {
    float4 v = row[c4];
    int cb = h * 32 + c4 * 4;
    s += v.x * asrc[cb] + v.y * asrc[cb + 1] + v.z * asrc[cb + 2] + v.w * asrc[cb + 3];
    d += v.x * adst[cb] + v.y * adst[cb + 1] + v.z * adst[cb + 2] + v.w * adst[cb + 3];
  }
  as1[i] = s;
  ad1[i] = d;
}

// ---------------- layer-1 aggregation + bias + relu + layer-2 GEMM + att2 ----------------
__global__ __launch_bounds__(256) void k_agg1(
    const float* __restrict__ h1, const float* __restrict__ as1,
    const float* __restrict__ ad1, const int* __restrict__ rowptr,
    const int* __restrict__ col, const float* __restrict__ b1,
    const float* __restrict__ W2, const float* __restrict__ asrc2,
    const float* __restrict__ adst2, float4* __restrict__ node2) {
  int wid = threadIdx.x >> 6, lane = threadIdx.x & 63;
  int node = blockIdx.x * 4 + wid;           // exact: 25000*4 = NN
  int head = lane >> 4;
  float ad = ad1[node * 4 + head];
  int beg = rowptr[node], end = rowptr[node + 1];
  const float2* h1v = (const float2*)h1;
  float accx = 0.f, accy = 0.f, wsum = 0.f;
  for (int j = beg; j < end; ++j) {
    int s = col[j];
    float e = as1[s * 4 + head] + ad;
    e = (e < 0.f) ? 0.2f * e : e;
    e = fminf(e, 80.f);                      // NaN guard (no-op when inputs sane)
    float w = __expf(e);
    wsum += w;
    float2 hv = h1v[(size_t)s * 64 + lane];
    accx += w * hv.x;
    accy += w * hv.y;
  }
  float inv = 1.f / (wsum + 1e-16f);
  float hx = accx * inv + b1[2 * lane];
  float hy = accy * inv + b1[2 * lane + 1];
  hx = (hx < 0.f) ? 0.01f * hx : hx;
  hy = (hy < 0.f) ? 0.01f * hy : hy;
  // layer-2 GEMM: h2[c] = sum_k hrelu[k] * W2[c][k]
  float p0 = hx * W2[2 * lane] + hy * W2[2 * lane + 1];
  float p1 = hx * W2[128 + 2 * lane] + hy * W2[128 + 2 * lane + 1];
#pragma unroll
  for (int d = 1; d < 64; d <<= 1) {
    p0 += __shfl_xor(p0, d, 64);
    p1 += __shfl_xor(p1, d, 64);
  }
  if (lane == 0) {
    float as2 = p0 * asrc2[0] + p1 * asrc2[1];
    float ad2 = p0 * adst2[0] + p1 * adst2[1];
    node2[node] = make_float4(p0, p1, as2, ad2);
  }
}

// ---------------- layer-2 aggregation + log_softmax ----------------
__global__ void k_agg2(const float4* __restrict__ node2, const int* __restrict__ rowptr,
                       const int* __restrict__ col, const float* __restrict__ b2,
                       float* __restrict__ out) {
  int i = blockIdx.x * 256 + threadIdx.x;
  if (i >= NN) return;
  float ad2 = node2[i].w;
  float den = 0.f, a0 = 0.f, a1 = 0.f;
  int beg = rowptr[i], end = rowptr[i + 1];
  for (int j = beg; j < end; ++j) {
    int s = col[j];
    float4 sv = node2[s];
    float e = sv.z + ad2;
    e = (e < 0.f) ? 0.2f * e : e;
    e = fminf(e, 80.f);                      // NaN guard
    float w = __expf(e);
    den += w;
    a0 += w * sv.x;
    a1 += w * sv.y;
  }
  float inv = 1.f / (den + 1e-16f);
  float o0 = a0 * inv + b2[0];
  float o1 = a1 * inv + b2[1];
  float m = fmaxf(o0, o1);
  float lse = m + __logf(__expf(o0 - m) + __expf(o1 - m));
  out[2 * i] = o0 - lse;
  out[2 * i + 1] = o1 - lse;
}

extern "C" void kernel_launch(void* const* d_in, const int* in_sizes, int n_in,
                              void* d_out, int out_size, void* d_ws, size_t ws_size,
                              hipStream_t stream) {
  const float* x     = (const float*)d_in[0];
  const int*   ei    = (const int*)d_in[1];
  const float* W1    = (const float*)d_in[2];
  const float* asrc1 = (const float*)d_in[3];
  const float* adst1 = (const float*)d_in[4];
  const float* b1    = (const float*)d_in[5];
  const float* W2    = (const float*)d_in[6];
  const float* asrc2 = (const float*)d_in[7];
  const float* adst2 = (const float*)d_in[8];
  const float* b2    = (const float*)d_in[9];
  float* out = (float*)d_out;

  // workspace layout
  int* rowptr = (int*)d_ws;                     // NN+1
  int* cursor = rowptr + 100352;
  int* deg    = cursor + 100352;
  int* col    = deg + 100352;                   // NTOT
  float*  h1   = (float*)(col + 1700096);       // NN*128
  float*  as1  = h1 + (size_t)NN * 128;         // NN*4
  float*  ad1  = as1 + NN * 4;                  // NN*4
  float4* node2 = (float4*)(ad1 + NN * 4);      // NN
  unsigned short* W1h = (unsigned short*)(node2 + NN);  // 16384
  unsigned short* W1l = W1h + 16384;                    // 16384

  k_init<<<(NN + 255) / 256, 256, 0, stream>>>(deg);
  k_hist<<<(NE + 255) / 256, 256, 0, stream>>>(ei, deg);
  k_scan<<<1, 1024, 0, stream>>>(deg, rowptr, cursor);
  k_scatter<<<(NTOT + 255) / 256, 256, 0, stream>>>(ei, cursor, col);
  k_cvtW<<<64, 256, 0, stream>>>(W1, W1h, W1l);
  k_gemm1<<<(NN / 16 + 3) / 4, 256, 0, stream>>>(x, W1h, W1l, h1);
  k_att1<<<(NN * 4 + 255) / 256, 256, 0, stream>>>(h1, asrc1, adst1, as1, ad1);
  k_agg1<<<NN / 4, 256, 0, stream>>>(h1, as1, ad1, rowptr, col, b1, W2, asrc2, adst2, node2);
  k_agg2<<<(NN + 255) / 256, 256, 0, stream>>>(node2, rowptr, col, b2, out);
}

// Round 3
// 540.096 us; speedup vs baseline: 1.2655x; 1.2655x over previous
//
#include <hip/hip_runtime.h>

#define NN 100000
#define NE 1600000
#define NTOT (NN + NE)

typedef __attribute__((ext_vector_type(8))) short bf16x8;
typedef __attribute__((ext_vector_type(4))) float f32x4;

__device__ __forceinline__ float bf2f(unsigned short u) {
  union { unsigned int i; float f; } v; v.i = ((unsigned int)u) << 16; return v.f;
}
__device__ __forceinline__ unsigned short f2bf(float f) {
  union { float f; unsigned int i; } v; v.f = f;
  unsigned int i = v.i;
  i += 0x7fffu + ((i >> 16) & 1u);
  return (unsigned short)(i >> 16);
}

// ---------------- CSR build ----------------
__global__ void k_init(int* __restrict__ deg) {
  int i = blockIdx.x * 256 + threadIdx.x;
  if (i < NN) deg[i] = 1;  // self-loop pre-counted
}

__global__ void k_hist(const int* __restrict__ ei, int* __restrict__ deg) {
  int e = blockIdx.x * 256 + threadIdx.x;
  if (e < NE) atomicAdd(&deg[ei[NE + e]], 1);
}

// hierarchical scan: 98 blocks x 1024 -> block-local exclusive + block sums
__global__ __launch_bounds__(1024) void k_scan1(const int* __restrict__ deg,
                                                int* __restrict__ rowptr,
                                                int* __restrict__ bsum) {
  __shared__ int ws[16];
  int tid = threadIdx.x, lane = tid & 63, wid = tid >> 6;
  int i = blockIdx.x * 1024 + tid;
  int v = (i < NN) ? deg[i] : 0;
  int x = v;
#pragma unroll
  for (int d = 1; d < 64; d <<= 1) {
    int y = __shfl_up(x, d, 64);
    if (lane >= d) x += y;
  }
  if (lane == 63) ws[wid] = x;
  __syncthreads();
  if (tid < 16) {
    int t = ws[tid];
    int xx = t;
#pragma unroll
    for (int d = 1; d < 16; d <<= 1) {
      int y = __shfl_up(xx, d, 16);
      if (tid >= d) xx += y;
    }
    ws[tid] = xx - t;  // exclusive wave offset
  }
  __syncthreads();
  if (i < NN) rowptr[i] = ws[wid] + (x - v);   // block-local exclusive
  if (tid == 1023) bsum[blockIdx.x] = ws[15] + x;  // block total
}

// scan the 98 block sums (2 waves)
__global__ void k_scan2(const int* __restrict__ bsum, int* __restrict__ boff,
                        int* __restrict__ rowptr) {
  __shared__ int w0sum;
  int tid = threadIdx.x, lane = tid & 63, wid = tid >> 6;
  int v = (tid < 98) ? bsum[tid] : 0;
  int x = v;
#pragma unroll
  for (int d = 1; d < 64; d <<= 1) {
    int y = __shfl_up(x, d, 64);
    if (lane >= d) x += y;
  }
  if (tid == 63) w0sum = x;
  __syncthreads();
  int incl = x + ((wid == 1) ? w0sum : 0);
  if (tid < 98) boff[tid] = incl - v;
  if (tid == 97) rowptr[NN] = incl;  // grand total = NTOT
}

__global__ __launch_bounds__(1024) void k_scan3(int* __restrict__ rowptr,
                                                const int* __restrict__ boff,
                                                int* __restrict__ cursor) {
  int i = blockIdx.x * 1024 + threadIdx.x;
  if (i < NN) {
    int r = rowptr[i] + boff[blockIdx.x];
    rowptr[i] = r;
    cursor[i] = r;
  }
}

__global__ void k_scatter(const int* __restrict__ ei, int* __restrict__ cursor,
                          int* __restrict__ col) {
  int t = blockIdx.x * 256 + threadIdx.x;
  if (t < NE) {
    int s = ei[t], d = ei[NE + t];
    col[atomicAdd(&cursor[d], 1)] = s;
  } else if (t < NTOT) {
    int nn = t - NE;
    col[atomicAdd(&cursor[nn], 1)] = nn;
  }
}

// ---------------- W1 hi/lo bf16 split (once) ----------------
__global__ void k_cvtW(const float* __restrict__ W1, unsigned short* __restrict__ Wh,
                       unsigned short* __restrict__ Wl) {
  int i = blockIdx.x * 256 + threadIdx.x;
  if (i < 128 * 128) {
    float v = W1[i];
    unsigned short h = f2bf(v);
    Wh[i] = h;
    Wl[i] = f2bf(v - bf2f(h));
  }
}

// ---------------- Layer 1 GEMM: h1 = x @ W1^T, fp32 via hi/lo split MFMA ----------------
__global__ __launch_bounds__(256) void k_gemm1(const float* __restrict__ x,
                                               const unsigned short* __restrict__ Wh,
                                               const unsigned short* __restrict__ Wl,
                                               float* __restrict__ h1) {
  int wid = threadIdx.x >> 6, lane = threadIdx.x & 63;
  int tile = blockIdx.x * 4 + wid;          // 16-node tile
  if (tile >= NN / 16) return;
  int r16 = lane & 15, quad = lane >> 4;
  const float* xrow = x + (size_t)(tile * 16 + r16) * 128 + quad * 8;
  bf16x8 ah[4], al[4];
#pragma unroll
  for (int c = 0; c < 4; ++c) {
#pragma unroll
    for (int j = 0; j < 8; ++j) {
      float v = xrow[c * 32 + j];
      unsigned short h = f2bf(v);
      ah[c][j] = (short)h;
      al[c][j] = (short)f2bf(v - bf2f(h));
    }
  }
#pragma unroll
  for (int ot = 0; ot < 8; ++ot) {
    const bf16x8* whrow = (const bf16x8*)(Wh + (size_t)(ot * 16 + r16) * 128);
    const bf16x8* wlrow = (const bf16x8*)(Wl + (size_t)(ot * 16 + r16) * 128);
    f32x4 acc = {0.f, 0.f, 0.f, 0.f};
#pragma unroll
    for (int c = 0; c < 4; ++c) {
      bf16x8 wh = whrow[c * 4 + quad];
      bf16x8 wl = wlrow[c * 4 + quad];
      acc = __builtin_amdgcn_mfma_f32_16x16x32_bf16(ah[c], wh, acc, 0, 0, 0);
      acc = __builtin_amdgcn_mfma_f32_16x16x32_bf16(ah[c], wl, acc, 0, 0, 0);
      acc = __builtin_amdgcn_mfma_f32_16x16x32_bf16(al[c], wh, acc, 0, 0, 0);
    }
    float* o = h1 + (size_t)(tile * 16 + quad * 4) * 128 + ot * 16 + r16;
    o[0] = acc[0]; o[128] = acc[1]; o[256] = acc[2]; o[384] = acc[3];
  }
}

// ---------------- attention coefficients layer 1 ----------------
__global__ void k_att1(const float* __restrict__ h1,
                       const float* __restrict__ asrc,
                       const float* __restrict__ adst,
                       float* __restrict__ as1, float* __restrict__ ad1) {
  int i = blockIdx.x * 256 + threadIdx.x;
  if (i >= NN * 4) return;
  int nn = i >> 2, h = i & 3;
  const float4* row = (const float4*)(h1 + (size_t)nn * 128 + h * 32);
  float s = 0.f, d = 0.f;
#pragma unroll
  for (int c4 = 0; c4 < 8; ++c4) {
    float4 v = row[c4];
    int cb = h * 32 + c4 * 4;
    s += v.x * asrc[cb] + v.y * asrc[cb + 1] + v.z * asrc[cb + 2] + v.w * asrc[cb + 3];
    d += v.x * adst[cb] + v.y * adst[cb + 1] + v.z * adst[cb + 2] + v.w * adst[cb + 3];
  }
  as1[i] = s;
  ad1[i] = d;
}

// ---------------- layer-1 aggregation + bias + relu + layer-2 GEMM + att2 ----------------
__global__ __launch_bounds__(256) void k_agg1(
    const float* __restrict__ h1, const float* __restrict__ as1,
    const float* __restrict__ ad1, const int* __restrict__ rowptr,
    const int* __restrict__ col, const float* __restrict__ b1,
    const float* __restrict__ W2, const float* __restrict__ asrc2,
    const float* __restrict__ adst2, float4* __restrict__ node2) {
  int wid = threadIdx.x >> 6, lane = threadIdx.x & 63;
  int node = blockIdx.x * 4 + wid;           // exact: 25000*4 = NN
  int head = lane >> 4;
  float ad = ad1[node * 4 + head];
  int beg = rowptr[node], end = rowptr[node + 1];
  const float2* h1v = (const float2*)h1;
  float accx = 0.f, accy = 0.f, wsum = 0.f;
  int j = beg;
  // unroll-4: 4 independent gather chains in flight per wave
  for (; j + 3 < end; j += 4) {
    int s0 = col[j], s1 = col[j + 1], s2 = col[j + 2], s3 = col[j + 3];
    float e0 = as1[s0 * 4 + head] + ad;
    float e1 = as1[s1 * 4 + head] + ad;
    float e2 = as1[s2 * 4 + head] + ad;
    float e3 = as1[s3 * 4 + head] + ad;
    float2 v0 = h1v[(size_t)s0 * 64 + lane];
    float2 v1 = h1v[(size_t)s1 * 64 + lane];
    float2 v2 = h1v[(size_t)s2 * 64 + lane];
    float2 v3 = h1v[(size_t)s3 * 64 + lane];
    e0 = (e0 < 0.f) ? 0.2f * e0 : e0;
    e1 = (e1 < 0.f) ? 0.2f * e1 : e1;
    e2 = (e2 < 0.f) ? 0.2f * e2 : e2;
    e3 = (e3 < 0.f) ? 0.2f * e3 : e3;
    float w0 = __expf(fminf(e0, 80.f));
    float w1 = __expf(fminf(e1, 80.f));
    float w2 = __expf(fminf(e2, 80.f));
    float w3 = __expf(fminf(e3, 80.f));
    wsum += (w0 + w1) + (w2 + w3);
    accx += w0 * v0.x + w1 * v1.x + w2 * v2.x + w3 * v3.x;
    accy += w0 * v0.y + w1 * v1.y + w2 * v2.y + w3 * v3.y;
  }
  for (; j < end; ++j) {
    int s = col[j];
    float e = as1[s * 4 + head] + ad;
    e = (e < 0.f) ? 0.2f * e : e;
    float w = __expf(fminf(e, 80.f));
    wsum += w;
    float2 hv = h1v[(size_t)s * 64 + lane];
    accx += w * hv.x;
    accy += w * hv.y;
  }
  float inv = 1.f / (wsum + 1e-16f);
  float hx = accx * inv + b1[2 * lane];
  float hy = accy * inv + b1[2 * lane + 1];
  hx = (hx < 0.f) ? 0.01f * hx : hx;
  hy = (hy < 0.f) ? 0.01f * hy : hy;
  float p0 = hx * W2[2 * lane] + hy * W2[2 * lane + 1];
  float p1 = hx * W2[128 + 2 * lane] + hy * W2[128 + 2 * lane + 1];
#pragma unroll
  for (int d = 1; d < 64; d <<= 1) {
    p0 += __shfl_xor(p0, d, 64);
    p1 += __shfl_xor(p1, d, 64);
  }
  if (lane == 0) {
    float as2 = p0 * asrc2[0] + p1 * asrc2[1];
    float ad2 = p0 * adst2[0] + p1 * adst2[1];
    node2[node] = make_float4(p0, p1, as2, ad2);
  }
}

// ---------------- layer-2 aggregation + log_softmax (4 lanes per node) ----------------
__global__ void k_agg2(const float4* __restrict__ node2, const int* __restrict__ rowptr,
                       const int* __restrict__ col, const float* __restrict__ b2,
                       float2* __restrict__ out) {
  int t = blockIdx.x * 256 + threadIdx.x;
  int node = t >> 2, sub = t & 3;
  if (node >= NN) return;
  float ad2 = node2[node].w;
  int beg = rowptr[node], end = rowptr[node + 1];
  float den = 0.f, a0 = 0.f, a1 = 0.f;
  for (int j = beg + sub; j < end; j += 4) {
    int s = col[j];
    float4 sv = node2[s];
    float e = sv.z + ad2;
    e = (e < 0.f) ? 0.2f * e : e;
    float w = __expf(fminf(e, 80.f));
    den += w;
    a0 += w * sv.x;
    a1 += w * sv.y;
  }
#pragma unroll
  for (int d = 1; d < 4; d <<= 1) {
    den += __shfl_xor(den, d, 64);
    a0 += __shfl_xor(a0, d, 64);
    a1 += __shfl_xor(a1, d, 64);
  }
  if (sub == 0) {
    float inv = 1.f / (den + 1e-16f);
    float o0 = a0 * inv + b2[0];
    float o1 = a1 * inv + b2[1];
    float m = fmaxf(o0, o1);
    float lse = m + __logf(__expf(o0 - m) + __expf(o1 - m));
    out[node] = make_float2(o0 - lse, o1 - lse);
  }
}

extern "C" void kernel_launch(void* const* d_in, const int* in_sizes, int n_in,
                              void* d_out, int out_size, void* d_ws, size_t ws_size,
                              hipStream_t stream) {
  const float* x     = (const float*)d_in[0];
  const int*   ei    = (const int*)d_in[1];
  const float* W1    = (const float*)d_in[2];
  const float* asrc1 = (const float*)d_in[3];
  const float* adst1 = (const float*)d_in[4];
  const float* b1    = (const float*)d_in[5];
  const float* W2    = (const float*)d_in[6];
  const float* asrc2 = (const float*)d_in[7];
  const float* adst2 = (const float*)d_in[8];
  const float* b2    = (const float*)d_in[9];
  float2* out = (float2*)d_out;

  // workspace layout
  int* rowptr = (int*)d_ws;                     // NN+1
  int* cursor = rowptr + 100352;
  int* deg    = cursor + 100352;
  int* col    = deg + 100352;                   // NTOT
  float*  h1   = (float*)(col + 1700096);       // NN*128
  float*  as1  = h1 + (size_t)NN * 128;         // NN*4
  float*  ad1  = as1 + NN * 4;                  // NN*4
  float4* node2 = (float4*)(ad1 + NN * 4);      // NN
  unsigned short* W1h = (unsigned short*)(node2 + NN);  // 16384
  unsigned short* W1l = W1h + 16384;                    // 16384
  int* bsum = (int*)(W1l + 16384);              // 128
  int* boff = bsum + 128;                       // 128

  k_init<<<(NN + 255) / 256, 256, 0, stream>>>(deg);
  k_hist<<<(NE + 255) / 256, 256, 0, stream>>>(ei, deg);
  k_scan1<<<98, 1024, 0, stream>>>(deg, rowptr, bsum);
  k_scan2<<<1, 128, 0, stream>>>(bsum, boff, rowptr);
  k_scan3<<<98, 1024, 0, stream>>>(rowptr, boff, cursor);
  k_scatter<<<(NTOT + 255) / 256, 256, 0, stream>>>(ei, cursor, col);
  k_cvtW<<<64, 256, 0, stream>>>(W1, W1h, W1l);
  k_gemm1<<<(NN / 16 + 3) / 4, 256, 0, stream>>>(x, W1h, W1l, h1);
  k_att1<<<(NN * 4 + 255) / 256, 256, 0, stream>>>(h1, asrc1, adst1, as1, ad1);
  k_agg1<<<NN / 4, 256, 0, stream>>>(h1, as1, ad1, rowptr, col, b1, W2, asrc2, adst2, node2);
  k_agg2<<<(NN * 4 + 255) / 256, 256, 0, stream>>>(node2, rowptr, col, b2, out);
}

// Round 4
// 448.867 us; speedup vs baseline: 1.5227x; 1.2032x over previous
//
#include <hip/hip_runtime.h>

#define NN 100000
#define NE 1600000
#define NTOT (NN + NE)

typedef __attribute__((ext_vector_type(8))) short bf16x8;
typedef __attribute__((ext_vector_type(4))) float f32x4;

static __device__ __forceinline__ float blo(unsigned int u) {
  union { unsigned int i; float f; } v; v.i = u << 16; return v.f;
}
static __device__ __forceinline__ float bhi(unsigned int u) {
  union { unsigned int i; float f; } v; v.i = u & 0xffff0000u; return v.f;
}
static __device__ __forceinline__ unsigned short f2bf(float f) {
  union { float f; unsigned int i; } v; v.f = f;
  unsigned int i = v.i;
  i += 0x7fffu + ((i >> 16) & 1u);
  return (unsigned short)(i >> 16);
}

// ---------------- CSR build ----------------
__global__ void k_init(int* __restrict__ deg) {
  int i = blockIdx.x * 256 + threadIdx.x;
  if (i < NN) deg[i] = 1;  // self-loop pre-counted
}

__global__ void k_hist(const int* __restrict__ ei, int* __restrict__ deg) {
  int e = blockIdx.x * 256 + threadIdx.x;
  if (e < NE) atomicAdd(&deg[ei[NE + e]], 1);
}

__global__ __launch_bounds__(1024) void k_scan1(const int* __restrict__ deg,
                                                int* __restrict__ rowptr,
                                                int* __restrict__ bsum) {
  __shared__ int ws[16];
  int tid = threadIdx.x, lane = tid & 63, wid = tid >> 6;
  int i = blockIdx.x * 1024 + tid;
  int v = (i < NN) ? deg[i] : 0;
  int x = v;
#pragma unroll
  for (int d = 1; d < 64; d <<= 1) {
    int y = __shfl_up(x, d, 64);
    if (lane >= d) x += y;
  }
  if (lane == 63) ws[wid] = x;
  __syncthreads();
  if (tid < 16) {
    int t = ws[tid];
    int xx = t;
#pragma unroll
    for (int d = 1; d < 16; d <<= 1) {
      int y = __shfl_up(xx, d, 16);
      if (tid >= d) xx += y;
    }
    ws[tid] = xx - t;
  }
  __syncthreads();
  if (i < NN) rowptr[i] = ws[wid] + (x - v);
  if (tid == 1023) bsum[blockIdx.x] = ws[15] + x;
}

__global__ void k_scan2(const int* __restrict__ bsum, int* __restrict__ boff,
                        int* __restrict__ rowptr) {
  __shared__ int w0sum;
  int tid = threadIdx.x, lane = tid & 63, wid = tid >> 6;
  int v = (tid < 98) ? bsum[tid] : 0;
  int x = v;
#pragma unroll
  for (int d = 1; d < 64; d <<= 1) {
    int y = __shfl_up(x, d, 64);
    if (lane >= d) x += y;
  }
  if (tid == 63) w0sum = x;
  __syncthreads();
  int incl = x + ((wid == 1) ? w0sum : 0);
  if (tid < 98) boff[tid] = incl - v;
  if (tid == 97) rowptr[NN] = incl;
}

__global__ __launch_bounds__(1024) void k_scan3(int* __restrict__ rowptr,
                                                const int* __restrict__ boff,
                                                int* __restrict__ cursor) {
  int i = blockIdx.x * 1024 + threadIdx.x;
  if (i < NN) {
    int r = rowptr[i] + boff[blockIdx.x];
    rowptr[i] = r;
    cursor[i] = r;
  }
}

__global__ void k_scatter(const int* __restrict__ ei, int* __restrict__ cursor,
                          int* __restrict__ col) {
  int t = blockIdx.x * 256 + threadIdx.x;
  if (t < NE) {
    int s = ei[t], d = ei[NE + t];
    col[atomicAdd(&cursor[d], 1)] = s;
  } else if (t < NTOT) {
    int nn = t - NE;
    col[atomicAdd(&cursor[nn], 1)] = nn;
  }
}

// ---------------- W1 hi/lo bf16 split (once) ----------------
__global__ void k_cvtW(const float* __restrict__ W1, unsigned short* __restrict__ Wh,
                       unsigned short* __restrict__ Wl) {
  int i = blockIdx.x * 256 + threadIdx.x;
  if (i < 128 * 128) {
    float v = W1[i];
    unsigned short h = f2bf(v);
    Wh[i] = h;
    Wl[i] = f2bf(v - blo((unsigned int)h));
  }
}

// ------- Layer 1 GEMM (fp32 via hi/lo MFMA) + fused attention coefs + bf16 h1 -------
__global__ __launch_bounds__(256) void k_gemm1(
    const float* __restrict__ x, const unsigned short* __restrict__ Wh,
    const unsigned short* __restrict__ Wl, const float* __restrict__ asrc,
    const float* __restrict__ adst, unsigned short* __restrict__ h1b,
    float4* __restrict__ as1, float4* __restrict__ ad1) {
  int wid = threadIdx.x >> 6, lane = threadIdx.x & 63;
  int tile = blockIdx.x * 4 + wid;
  if (tile >= NN / 16) return;
  int r16 = lane & 15, quad = lane >> 4;
  const float* xrow = x + (size_t)(tile * 16 + r16) * 128 + quad * 8;
  bf16x8 ah[4], al[4];
#pragma unroll
  for (int c = 0; c < 4; ++c)
#pragma unroll
    for (int j = 0; j < 8; ++j) {
      float v = xrow[c * 32 + j];
      unsigned short h = f2bf(v);
      ah[c][j] = (short)h;
      al[c][j] = (short)f2bf(v - blo((unsigned int)h));
    }
  float asp[4][4], adp[4][4];
#pragma unroll
  for (int h = 0; h < 4; ++h)
#pragma unroll
    for (int r = 0; r < 4; ++r) { asp[h][r] = 0.f; adp[h][r] = 0.f; }
#pragma unroll
  for (int ot = 0; ot < 8; ++ot) {
    const bf16x8* whrow = (const bf16x8*)(Wh + (size_t)(ot * 16 + r16) * 128);
    const bf16x8* wlrow = (const bf16x8*)(Wl + (size_t)(ot * 16 + r16) * 128);
    f32x4 acc = {0.f, 0.f, 0.f, 0.f};
#pragma unroll
    for (int c = 0; c < 4; ++c) {
      bf16x8 wh = whrow[c * 4 + quad];
      bf16x8 wl = wlrow[c * 4 + quad];
      acc = __builtin_amdgcn_mfma_f32_16x16x32_bf16(ah[c], wh, acc, 0, 0, 0);
      acc = __builtin_amdgcn_mfma_f32_16x16x32_bf16(ah[c], wl, acc, 0, 0, 0);
      acc = __builtin_amdgcn_mfma_f32_16x16x32_bf16(al[c], wh, acc, 0, 0, 0);
    }
    // fused attention partials: col = ot*16 + r16, head = ot>>1
    float sa = asrc[ot * 16 + r16], da = adst[ot * 16 + r16];
    const int hh = ot >> 1;
#pragma unroll
    for (int r = 0; r < 4; ++r) {
      asp[hh][r] += acc[r] * sa;
      adp[hh][r] += acc[r] * da;
    }
    // bf16 h1 store: D row = quad*4+reg, col = ot*16+r16
    unsigned short* o = h1b + (size_t)(tile * 16 + quad * 4) * 128 + ot * 16 + r16;
    o[0] = f2bf(acc[0]); o[128] = f2bf(acc[1]);
    o[256] = f2bf(acc[2]); o[384] = f2bf(acc[3]);
  }
  // reduce attention partials across the 16 col-lanes (butterfly within r16 bits)
#pragma unroll
  for (int h = 0; h < 4; ++h)
#pragma unroll
    for (int r = 0; r < 4; ++r) {
      float v = asp[h][r];
      v += __shfl_xor(v, 1, 64); v += __shfl_xor(v, 2, 64);
      v += __shfl_xor(v, 4, 64); v += __shfl_xor(v, 8, 64);
      asp[h][r] = v;
      float w = adp[h][r];
      w += __shfl_xor(w, 1, 64); w += __shfl_xor(w, 2, 64);
      w += __shfl_xor(w, 4, 64); w += __shfl_xor(w, 8, 64);
      adp[h][r] = w;
    }
#pragma unroll
  for (int r = 0; r < 4; ++r) {
    if (r16 == r) {  // compile-time index, predicated store
      int node = tile * 16 + quad * 4 + r;
      as1[node] = make_float4(asp[0][r], asp[1][r], asp[2][r], asp[3][r]);
      ad1[node] = make_float4(adp[0][r], adp[1][r], adp[2][r], adp[3][r]);
    }
  }
}

// ------- layer-1 aggregation (bf16 gathers) + bias + relu + layer-2 GEMM + att2 -------
__global__ __launch_bounds__(256, 8) void k_agg1(
    const unsigned short* __restrict__ h1b, const float* __restrict__ as1,
    const float* __restrict__ ad1, const int* __restrict__ rowptr,
    const int* __restrict__ col, const float* __restrict__ b1,
    const float* __restrict__ W2, const float* __restrict__ asrc2,
    const float* __restrict__ adst2, float4* __restrict__ node2) {
  int wid = threadIdx.x >> 6, lane = threadIdx.x & 63;
  int node = blockIdx.x * 4 + wid;           // exact: 25000*4 = NN
  int head = lane >> 4;
  float ad = ad1[node * 4 + head];
  int beg = rowptr[node], end = rowptr[node + 1];
  const unsigned int* h1u = (const unsigned int*)h1b;  // row stride 64 uints
  float accx = 0.f, accy = 0.f, wsum = 0.f;
  int j = beg;
  for (; j + 7 < end; j += 8) {   // 8 independent gather chains in flight
    int s[8]; float e[8]; unsigned int u[8];
#pragma unroll
    for (int k = 0; k < 8; ++k) s[k] = col[j + k];
#pragma unroll
    for (int k = 0; k < 8; ++k) e[k] = as1[s[k] * 4 + head] + ad;
#pragma unroll
    for (int k = 0; k < 8; ++k) u[k] = h1u[(size_t)s[k] * 64 + lane];
#pragma unroll
    for (int k = 0; k < 8; ++k) {
      float t = e[k];
      t = (t < 0.f) ? 0.2f * t : t;
      float w = __expf(fminf(t, 80.f));
      wsum += w;
      accx += w * blo(u[k]);
      accy += w * bhi(u[k]);
    }
  }
  for (; j < end; ++j) {
    int s = col[j];
    float t = as1[s * 4 + head] + ad;
    t = (t < 0.f) ? 0.2f * t : t;
    float w = __expf(fminf(t, 80.f));
    wsum += w;
    unsigned int u = h1u[(size_t)s * 64 + lane];
    accx += w * blo(u);
    accy += w * bhi(u);
  }
  float inv = 1.f / (wsum + 1e-16f);
  float hx = accx * inv + b1[2 * lane];
  float hy = accy * inv + b1[2 * lane + 1];
  hx = (hx < 0.f) ? 0.01f * hx : hx;
  hy = (hy < 0.f) ? 0.01f * hy : hy;
  float p0 = hx * W2[2 * lane] + hy * W2[2 * lane + 1];
  float p1 = hx * W2[128 + 2 * lane] + hy * W2[128 + 2 * lane + 1];
#pragma unroll
  for (int d = 1; d < 64; d <<= 1) {
    p0 += __shfl_xor(p0, d, 64);
    p1 += __shfl_xor(p1, d, 64);
  }
  if (lane == 0) {
    float as2 = p0 * asrc2[0] + p1 * asrc2[1];
    float ad2 = p0 * adst2[0] + p1 * adst2[1];
    node2[node] = make_float4(p0, p1, as2, ad2);
  }
}

// ---------------- layer-2 aggregation + log_softmax (4 lanes per node) ----------------
__global__ void k_agg2(const float4* __restrict__ node2, const int* __restrict__ rowptr,
                       const int* __restrict__ col, const float* __restrict__ b2,
                       float2* __restrict__ out) {
  int t = blockIdx.x * 256 + threadIdx.x;
  int node = t >> 2, sub = t & 3;
  if (node >= NN) return;
  float ad2 = node2[node].w;
  int beg = rowptr[node], end = rowptr[node + 1];
  float den = 0.f, a0 = 0.f, a1 = 0.f;
  for (int j = beg + sub; j < end; j += 4) {
    int s = col[j];
    float4 sv = node2[s];
    float e = sv.z + ad2;
    e = (e < 0.f) ? 0.2f * e : e;
    float w = __expf(fminf(e, 80.f));
    den += w;
    a0 += w * sv.x;
    a1 += w * sv.y;
  }
#pragma unroll
  for (int d = 1; d < 4; d <<= 1) {
    den += __shfl_xor(den, d, 64);
    a0 += __shfl_xor(a0, d, 64);
    a1 += __shfl_xor(a1, d, 64);
  }
  if (sub == 0) {
    float inv = 1.f / (den + 1e-16f);
    float o0 = a0 * inv + b2[0];
    float o1 = a1 * inv + b2[1];
    float m = fmaxf(o0, o1);
    float lse = m + __logf(__expf(o0 - m) + __expf(o1 - m));
    out[node] = make_float2(o0 - lse, o1 - lse);
  }
}

extern "C" void kernel_launch(void* const* d_in, const int* in_sizes, int n_in,
                              void* d_out, int out_size, void* d_ws, size_t ws_size,
                              hipStream_t stream) {
  const float* x     = (const float*)d_in[0];
  const int*   ei    = (const int*)d_in[1];
  const float* W1    = (const float*)d_in[2];
  const float* asrc1 = (const float*)d_in[3];
  const float* adst1 = (const float*)d_in[4];
  const float* b1    = (const float*)d_in[5];
  const float* W2    = (const float*)d_in[6];
  const float* asrc2 = (const float*)d_in[7];
  const float* adst2 = (const float*)d_in[8];
  const float* b2    = (const float*)d_in[9];
  float2* out = (float2*)d_out;

  // workspace layout (16B-aligned chunks)
  int* rowptr = (int*)d_ws;                            // 100352
  int* cursor = rowptr + 100352;
  int* deg    = cursor + 100352;
  int* col    = deg + 100352;                          // 1700096
  unsigned short* h1b = (unsigned short*)(col + 1700096);  // NN*128 bf16 = 25.6MB
  float*  as1  = (float*)(h1b + (size_t)NN * 128);     // NN*4
  float*  ad1  = as1 + NN * 4;                         // NN*4
  float4* node2 = (float4*)(ad1 + NN * 4);             // NN
  unsigned short* W1h = (unsigned short*)(node2 + NN); // 16384
  unsigned short* W1l = W1h + 16384;                   // 16384
  int* bsum = (int*)(W1l + 16384);                     // 128
  int* boff = bsum + 128;                              // 128

  k_init<<<(NN + 255) / 256, 256, 0, stream>>>(deg);
  k_hist<<<(NE + 255) / 256, 256, 0, stream>>>(ei, deg);
  k_scan1<<<98, 1024, 0, stream>>>(deg, rowptr, bsum);
  k_scan2<<<1, 128, 0, stream>>>(bsum, boff, rowptr);
  k_scan3<<<98, 1024, 0, stream>>>(rowptr, boff, cursor);
  k_scatter<<<(NTOT + 255) / 256, 256, 0, stream>>>(ei, cursor, col);
  k_cvtW<<<64, 256, 0, stream>>>(W1, W1h, W1l);
  k_gemm1<<<(NN / 16 + 3) / 4, 256, 0, stream>>>(x, W1h, W1l, asrc1, adst1, h1b,
                                                 (float4*)as1, (float4*)ad1);
  k_agg1<<<NN / 4, 256, 0, stream>>>(h1b, as1, ad1, rowptr, col, b1, W2, asrc2, adst2, node2);
  k_agg2<<<(NN * 4 + 255) / 256, 256, 0, stream>>>(node2, rowptr, col, b2, out);
}

// Round 5
// 317.673 us; speedup vs baseline: 2.1516x; 1.4130x over previous
//
#include <hip/hip_runtime.h>

#define NN 100000
#define NE 1600000
#define NTOT (NN + NE)
#define NB 391            // buckets of 256 dst nodes
#define ACHUNK 4096       // edges per phase-A block
#define BCAP 6144         // phase-B LDS col capacity (mean 4096+160, sigma 64)

typedef __attribute__((ext_vector_type(8))) short bf16x8;
typedef __attribute__((ext_vector_type(4))) float f32x4;

static __device__ __forceinline__ float blo(unsigned int u) {
  union { unsigned int i; float f; } v; v.i = u << 16; return v.f;
}
static __device__ __forceinline__ float bhi(unsigned int u) {
  union { unsigned int i; float f; } v; v.i = u & 0xffff0000u; return v.f;
}
static __device__ __forceinline__ unsigned short f2bf(float f) {
  union { float f; unsigned int i; } v; v.f = f;
  unsigned int i = v.i;
  i += 0x7fffu + ((i >> 16) & 1u);
  return (unsigned short)(i >> 16);
}

// ---------------- CSR build: two-phase LDS-binned counting sort ----------------
__global__ void k_zero(int* __restrict__ bucketCnt) {
  int i = threadIdx.x;
  if (i < NB) bucketCnt[i] = 0;
}

__global__ __launch_bounds__(256) void kb_hist(const int* __restrict__ ei,
                                               int* __restrict__ bucketCnt) {
  __shared__ int h[NB];
  int tid = threadIdx.x;
  for (int i = tid; i < NB; i += 256) h[i] = 0;
  __syncthreads();
  for (int i = blockIdx.x * 256 + tid; i < NE; i += gridDim.x * 256)
    atomicAdd(&h[ei[NE + i] >> 8], 1);
  __syncthreads();
  for (int i = tid; i < NB; i += 256)
    if (h[i]) atomicAdd(&bucketCnt[i], h[i]);
}

// single-wave exclusive scan of NB counters -> pairOffset[0..NB], cursor init
__global__ void kb_scan(const int* __restrict__ bucketCnt, int* __restrict__ pairOffset,
                        int* __restrict__ bucketCursor) {
  int lane = threadIdx.x;  // 64 threads
  int c[7];
  int run = 0;
  int idx0 = lane * 7;
#pragma unroll
  for (int k = 0; k < 7; ++k) {
    int idx = idx0 + k;
    int v = (idx < NB) ? bucketCnt[idx] : 0;
    c[k] = run;
    run += v;
  }
  int x = run;
#pragma unroll
  for (int d = 1; d < 64; d <<= 1) {
    int y = __shfl_up(x, d, 64);
    if (lane >= d) x += y;
  }
  int laneoff = x - run;
#pragma unroll
  for (int k = 0; k < 7; ++k) {
    int idx = idx0 + k;
    if (idx <= NB) {
      int e = laneoff + c[k];
      pairOffset[idx] = e;
      if (idx < NB) bucketCursor[idx] = e;
    }
  }
}

// Phase A: bucket-sort edges into pair[] (packed (s<<8)|dlocal), coalesced runs
__global__ __launch_bounds__(256) void kb_scatA(const int* __restrict__ ei,
                                                int* __restrict__ bucketCursor,
                                                int* __restrict__ pair) {
  __shared__ int lcnt[NB + 1];   // hist -> exclusive offsets (sentinel at NB)
  __shared__ int gbase[NB];
  __shared__ int lcur[NB];
  __shared__ int stage[ACHUNK];
  int tid = threadIdx.x;
  int e0 = blockIdx.x * ACHUNK;
  int n = min(ACHUNK, NE - e0);
  for (int i = tid; i <= NB; i += 256) lcnt[i] = 0;
  __syncthreads();
  for (int i = tid; i < n; i += 256) atomicAdd(&lcnt[ei[NE + e0 + i] >> 8], 1);
  __syncthreads();
  if (tid < 64) {  // wave-0 scan of lcnt -> exclusive (in place), lcnt[NB] = n
    int c[7];
    int run = 0;
    int idx0 = tid * 7;
#pragma unroll
    for (int k = 0; k < 7; ++k) {
      int idx = idx0 + k;
      int v = (idx < NB) ? lcnt[idx] : 0;
      c[k] = run;
      run += v;
    }
    int x = run;
#pragma unroll
    for (int d = 1; d < 64; d <<= 1) {
      int y = __shfl_up(x, d, 64);
      if (tid >= d) x += y;
    }
    int laneoff = x - run;
#pragma unroll
    for (int k = 0; k < 7; ++k) {
      int idx = idx0 + k;
      if (idx <= NB) lcnt[idx] = laneoff + c[k];
    }
  }
  __syncthreads();
  for (int b = tid; b < NB; b += 256) {
    int cnt = lcnt[b + 1] - lcnt[b];
    gbase[b] = cnt ? atomicAdd(&bucketCursor[b], cnt) : 0;
    lcur[b] = lcnt[b];
  }
  __syncthreads();
  for (int i = tid; i < n; i += 256) {
    int s = ei[e0 + i], d = ei[NE + e0 + i];
    int b = d >> 8;
    int p = atomicAdd(&lcur[b], 1);
    stage[p] = (s << 8) | (d & 255);
  }
  __syncthreads();
  // stream out: slot i -> bucket via binary search; consecutive i -> consecutive global
  for (int i = tid; i < n; i += 256) {
    int lo = 0, hi = NB;
    while (hi - lo > 1) {
      int mid = (lo + hi) >> 1;
      if (lcnt[mid] <= i) lo = mid; else hi = mid;
    }
    pair[gbase[lo] + (i - lcnt[lo])] = stage[i];
  }
}

// Phase B: per bucket, exact CSR placement in LDS, coalesced col/rowptr writes
__global__ __launch_bounds__(256) void kb_binB(const int* __restrict__ pair,
                                               const int* __restrict__ pairOffset,
                                               int* __restrict__ rowptr,
                                               int* __restrict__ col) {
  __shared__ int lcnt2[256];
  __shared__ int lwsum[4];
  __shared__ int stage[BCAP];
  int tid = threadIdx.x, lane = tid & 63, wid = tid >> 6;
  int b = blockIdx.x;
  int dbase = b << 8;
  int nd = min(256, NN - dbase);
  int pbeg = pairOffset[b], pend = pairOffset[b + 1];
  int m = pend - pbeg;
  int cbase = pbeg + (b << 8);  // colOffset: +256 self-loops per preceding bucket
  lcnt2[tid] = 0;
  __syncthreads();
  for (int i = tid; i < m; i += 256) atomicAdd(&lcnt2[pair[pbeg + i] & 255], 1);
  __syncthreads();
  int deg = lcnt2[tid] + (tid < nd ? 1 : 0);  // +1 self-loop
  int x = deg;
#pragma unroll
  for (int d = 1; d < 64; d <<= 1) {
    int y = __shfl_up(x, d, 64);
    if (lane >= d) x += y;
  }
  if (lane == 63) lwsum[wid] = x;
  __syncthreads();
  int woff = 0;
  for (int w = 0; w < wid; ++w) woff += lwsum[w];
  int excl = woff + x - deg;
  if (tid < nd) {
    rowptr[dbase + tid] = cbase + excl;
    stage[excl] = dbase + tid;    // self-loop first
    lcnt2[tid] = excl + 1;        // cursor
  } else {
    lcnt2[tid] = excl;
  }
  if (b == NB - 1 && tid == 0) rowptr[NN] = NTOT;
  __syncthreads();
  for (int i = tid; i < m; i += 256) {
    int p = pair[pbeg + i];
    int pos = atomicAdd(&lcnt2[p & 255], 1);
    stage[pos] = p >> 8;
  }
  __syncthreads();
  int tot = m + nd;
  for (int i = tid; i < tot; i += 256) col[cbase + i] = stage[i];
}

// ---------------- W1 hi/lo bf16 split (once) ----------------
__global__ void k_cvtW(const float* __restrict__ W1, unsigned short* __restrict__ Wh,
                       unsigned short* __restrict__ Wl) {
  int i = blockIdx.x * 256 + threadIdx.x;
  if (i < 128 * 128) {
    float v = W1[i];
    unsigned short h = f2bf(v);
    Wh[i] = h;
    Wl[i] = f2bf(v - blo((unsigned int)h));
  }
}

// ------- Layer 1 GEMM (fp32 via hi/lo MFMA) + fused attention coefs + bf16 h1 -------
__global__ __launch_bounds__(256) void k_gemm1(
    const float* __restrict__ x, const unsigned short* __restrict__ Wh,
    const unsigned short* __restrict__ Wl, const float* __restrict__ asrc,
    const float* __restrict__ adst, unsigned short* __restrict__ h1b,
    float4* __restrict__ as1, float4* __restrict__ ad1) {
  int wid = threadIdx.x >> 6, lane = threadIdx.x & 63;
  int tile = blockIdx.x * 4 + wid;
  if (tile >= NN / 16) return;
  int r16 = lane & 15, quad = lane >> 4;
  const float* xrow = x + (size_t)(tile * 16 + r16) * 128 + quad * 8;
  bf16x8 ah[4], al[4];
#pragma unroll
  for (int c = 0; c < 4; ++c)
#pragma unroll
    for (int j = 0; j < 8; ++j) {
      float v = xrow[c * 32 + j];
      unsigned short h = f2bf(v);
      ah[c][j] = (short)h;
      al[c][j] = (short)f2bf(v - blo((unsigned int)h));
    }
  float asp[4][4], adp[4][4];
#pragma unroll
  for (int h = 0; h < 4; ++h)
#pragma unroll
    for (int r = 0; r < 4; ++r) { asp[h][r] = 0.f; adp[h][r] = 0.f; }
#pragma unroll
  for (int ot = 0; ot < 8; ++ot) {
    const bf16x8* whrow = (const bf16x8*)(Wh + (size_t)(ot * 16 + r16) * 128);
    const bf16x8* wlrow = (const bf16x8*)(Wl + (size_t)(ot * 16 + r16) * 128);
    f32x4 acc = {0.f, 0.f, 0.f, 0.f};
#pragma unroll
    for (int c = 0; c < 4; ++c) {
      bf16x8 wh = whrow[c * 4 + quad];
      bf16x8 wl = wlrow[c * 4 + quad];
      acc = __builtin_amdgcn_mfma_f32_16x16x32_bf16(ah[c], wh, acc, 0, 0, 0);
      acc = __builtin_amdgcn_mfma_f32_16x16x32_bf16(ah[c], wl, acc, 0, 0, 0);
      acc = __builtin_amdgcn_mfma_f32_16x16x32_bf16(al[c], wh, acc, 0, 0, 0);
    }
    float sa = asrc[ot * 16 + r16], da = adst[ot * 16 + r16];
    const int hh = ot >> 1;
#pragma unroll
    for (int r = 0; r < 4; ++r) {
      asp[hh][r] += acc[r] * sa;
      adp[hh][r] += acc[r] * da;
    }
    unsigned short* o = h1b + (size_t)(tile * 16 + quad * 4) * 128 + ot * 16 + r16;
    o[0] = f2bf(acc[0]); o[128] = f2bf(acc[1]);
    o[256] = f2bf(acc[2]); o[384] = f2bf(acc[3]);
  }
#pragma unroll
  for (int h = 0; h < 4; ++h)
#pragma unroll
    for (int r = 0; r < 4; ++r) {
      float v = asp[h][r];
      v += __shfl_xor(v, 1, 64); v += __shfl_xor(v, 2, 64);
      v += __shfl_xor(v, 4, 64); v += __shfl_xor(v, 8, 64);
      asp[h][r] = v;
      float w = adp[h][r];
      w += __shfl_xor(w, 1, 64); w += __shfl_xor(w, 2, 64);
      w += __shfl_xor(w, 4, 64); w += __shfl_xor(w, 8, 64);
      adp[h][r] = w;
    }
#pragma unroll
  for (int r = 0; r < 4; ++r) {
    if (r16 == r) {
      int node = tile * 16 + quad * 4 + r;
      as1[node] = make_float4(asp[0][r], asp[1][r], asp[2][r], asp[3][r]);
      ad1[node] = make_float4(adp[0][r], adp[1][r], adp[2][r], adp[3][r]);
    }
  }
}

// ------- layer-1 aggregation (bf16 gathers) + bias + relu + layer-2 GEMM + att2 -------
__global__ __launch_bounds__(256, 8) void k_agg1(
    const unsigned short* __restrict__ h1b, const float* __restrict__ as1,
    const float* __restrict__ ad1, const int* __restrict__ rowptr,
    const int* __restrict__ col, const float* __restrict__ b1,
    const float* __restrict__ W2, const float* __restrict__ asrc2,
    const float* __restrict__ adst2, float4* __restrict__ node2) {
  int wid = threadIdx.x >> 6, lane = threadIdx.x & 63;
  int node = blockIdx.x * 4 + wid;           // exact: 25000*4 = NN
  int head = lane >> 4;
  float ad = ad1[node * 4 + head];
  int beg = rowptr[node], end = rowptr[node + 1];
  const unsigned int* h1u = (const unsigned int*)h1b;  // row stride 64 uints
  float accx = 0.f, accy = 0.f, wsum = 0.f;
  int j = beg;
  for (; j + 7 < end; j += 8) {   // 8 independent gather chains in flight
    int s[8]; float e[8]; unsigned int u[8];
#pragma unroll
    for (int k = 0; k < 8; ++k) s[k] = col[j + k];
#pragma unroll
    for (int k = 0; k < 8; ++k) e[k] = as1[s[k] * 4 + head] + ad;
#pragma unroll
    for (int k = 0; k < 8; ++k) u[k] = h1u[(size_t)s[k] * 64 + lane];
#pragma unroll
    for (int k = 0; k < 8; ++k) {
      float t = e[k];
      t = (t < 0.f) ? 0.2f * t : t;
      float w = __expf(fminf(t, 80.f));
      wsum += w;
      accx += w * blo(u[k]);
      accy += w * bhi(u[k]);
    }
  }
  for (; j < end; ++j) {
    int s = col[j];
    float t = as1[s * 4 + head] + ad;
    t = (t < 0.f) ? 0.2f * t : t;
    float w = __expf(fminf(t, 80.f));
    wsum += w;
    unsigned int u = h1u[(size_t)s * 64 + lane];
    accx += w * blo(u);
    accy += w * bhi(u);
  }
  float inv = 1.f / (wsum + 1e-16f);
  float hx = accx * inv + b1[2 * lane];
  float hy = accy * inv + b1[2 * lane + 1];
  hx = (hx < 0.f) ? 0.01f * hx : hx;
  hy = (hy < 0.f) ? 0.01f * hy : hy;
  float p0 = hx * W2[2 * lane] + hy * W2[2 * lane + 1];
  float p1 = hx * W2[128 + 2 * lane] + hy * W2[128 + 2 * lane + 1];
#pragma unroll
  for (int d = 1; d < 64; d <<= 1) {
    p0 += __shfl_xor(p0, d, 64);
    p1 += __shfl_xor(p1, d, 64);
  }
  if (lane == 0) {
    float as2 = p0 * asrc2[0] + p1 * asrc2[1];
    float ad2 = p0 * adst2[0] + p1 * adst2[1];
    node2[node] = make_float4(p0, p1, as2, ad2);
  }
}

// ---------------- layer-2 aggregation + log_softmax (4 lanes per node) ----------------
__global__ void k_agg2(const float4* __restrict__ node2, const int* __restrict__ rowptr,
                       const int* __restrict__ col, const float* __restrict__ b2,
                       float2* __restrict__ out) {
  int t = blockIdx.x * 256 + threadIdx.x;
  int node = t >> 2, sub = t & 3;
  if (node >= NN) return;
  float ad2 = node2[node].w;
  int beg = rowptr[node], end = rowptr[node + 1];
  float den = 0.f, a0 = 0.f, a1 = 0.f;
  for (int j = beg + sub; j < end; j += 4) {
    int s = col[j];
    float4 sv = node2[s];
    float e = sv.z + ad2;
    e = (e < 0.f) ? 0.2f * e : e;
    float w = __expf(fminf(e, 80.f));
    den += w;
    a0 += w * sv.x;
    a1 += w * sv.y;
  }
#pragma unroll
  for (int d = 1; d < 4; d <<= 1) {
    den += __shfl_xor(den, d, 64);
    a0 += __shfl_xor(a0, d, 64);
    a1 += __shfl_xor(a1, d, 64);
  }
  if (sub == 0) {
    float inv = 1.f / (den + 1e-16f);
    float o0 = a0 * inv + b2[0];
    float o1 = a1 * inv + b2[1];
    float m = fmaxf(o0, o1);
    float lse = m + __logf(__expf(o0 - m) + __expf(o1 - m));
    out[node] = make_float2(o0 - lse, o1 - lse);
  }
}

extern "C" void kernel_launch(void* const* d_in, const int* in_sizes, int n_in,
                              void* d_out, int out_size, void* d_ws, size_t ws_size,
                              hipStream_t stream) {
  const float* x     = (const float*)d_in[0];
  const int*   ei    = (const int*)d_in[1];
  const float* W1    = (const float*)d_in[2];
  const float* asrc1 = (const float*)d_in[3];
  const float* adst1 = (const float*)d_in[4];
  const float* b1    = (const float*)d_in[5];
  const float* W2    = (const float*)d_in[6];
  const float* asrc2 = (const float*)d_in[7];
  const float* adst2 = (const float*)d_in[8];
  const float* b2    = (const float*)d_in[9];
  float2* out = (float2*)d_out;

  // workspace layout (all 4B units; h1b offset keeps 16B alignment)
  int* rowptr       = (int*)d_ws;                  // 100352
  int* col          = rowptr + 100352;             // 1700096
  int* pair         = col + 1700096;               // 1600000
  int* bucketCnt    = pair + 1600000;              // 512
  int* pairOffset   = bucketCnt + 512;             // 512
  int* bucketCursor = pairOffset + 512;            // 512
  unsigned short* h1b = (unsigned short*)(bucketCursor + 512);  // NN*128 bf16
  float*  as1  = (float*)(h1b + (size_t)NN * 128); // NN*4
  float*  ad1  = as1 + NN * 4;                     // NN*4
  float4* node2 = (float4*)(ad1 + NN * 4);         // NN
  unsigned short* W1h = (unsigned short*)(node2 + NN);  // 16384
  unsigned short* W1l = W1h + 16384;                    // 16384

  k_zero<<<1, 512, 0, stream>>>(bucketCnt);
  kb_hist<<<391, 256, 0, stream>>>(ei, bucketCnt);
  kb_scan<<<1, 64, 0, stream>>>(bucketCnt, pairOffset, bucketCursor);
  kb_scatA<<<391, 256, 0, stream>>>(ei, bucketCursor, pair);
  kb_binB<<<NB, 256, 0, stream>>>(pair, pairOffset, rowptr, col);
  k_cvtW<<<64, 256, 0, stream>>>(W1, W1h, W1l);
  k_gemm1<<<(NN / 16 + 3) / 4, 256, 0, stream>>>(x, W1h, W1l, asrc1, adst1, h1b,
                                                 (float4*)as1, (float4*)ad1);
  k_agg1<<<NN / 4, 256, 0, stream>>>(h1b, as1, ad1, rowptr, col, b1, W2, asrc2, adst2, node2);
  k_agg2<<<(NN * 4 + 255) / 256, 256, 0, stream>>>(node2, rowptr, col, b2, out);
}

// Round 6
// 316.670 us; speedup vs baseline: 2.1584x; 1.0032x over previous
//
#include <hip/hip_runtime.h>

#define NN 100000
#define NE 1600000
#define NTOT (NN + NE)
#define NB 782            // buckets of 128 dst nodes
#define ACHUNK 4096       // edges per phase-A block
#define BCAP 3072         // phase-B LDS col capacity (mean 2048+128, sigma ~45)

typedef __attribute__((ext_vector_type(8))) short bf16x8;
typedef __attribute__((ext_vector_type(4))) float f32x4;

static __device__ __forceinline__ float blo(unsigned int u) {
  union { unsigned int i; float f; } v; v.i = u << 16; return v.f;
}
static __device__ __forceinline__ float bhi(unsigned int u) {
  union { unsigned int i; float f; } v; v.i = u & 0xffff0000u; return v.f;
}
static __device__ __forceinline__ unsigned short f2bf(float f) {
  union { float f; unsigned int i; } v; v.f = f;
  unsigned int i = v.i;
  i += 0x7fffu + ((i >> 16) & 1u);
  return (unsigned short)(i >> 16);
}

// ---------------- CSR build: two-phase LDS-binned counting sort ----------------
__global__ void k_zero(int* __restrict__ bucketCnt) {
  int i = threadIdx.x;
  if (i < NB) bucketCnt[i] = 0;
}

__global__ __launch_bounds__(256) void kb_hist(const int* __restrict__ ei,
                                               int* __restrict__ bucketCnt) {
  __shared__ int h[NB];
  int tid = threadIdx.x;
  for (int i = tid; i < NB; i += 256) h[i] = 0;
  __syncthreads();
  for (int i = blockIdx.x * 256 + tid; i < NE; i += gridDim.x * 256)
    atomicAdd(&h[ei[NE + i] >> 7], 1);
  __syncthreads();
  for (int i = tid; i < NB; i += 256)
    if (h[i]) atomicAdd(&bucketCnt[i], h[i]);
}

// single-wave exclusive scan of NB counters -> pairOffset[0..NB], cursor init
__global__ void kb_scan(const int* __restrict__ bucketCnt, int* __restrict__ pairOffset,
                        int* __restrict__ bucketCursor) {
  int lane = threadIdx.x;  // 64 threads, 13 chunks each (64*13=832 >= 783)
  int c[13];
  int run = 0;
  int idx0 = lane * 13;
#pragma unroll
  for (int k = 0; k < 13; ++k) {
    int idx = idx0 + k;
    int v = (idx < NB) ? bucketCnt[idx] : 0;
    c[k] = run;
    run += v;
  }
  int x = run;
#pragma unroll
  for (int d = 1; d < 64; d <<= 1) {
    int y = __shfl_up(x, d, 64);
    if (lane >= d) x += y;
  }
  int laneoff = x - run;
#pragma unroll
  for (int k = 0; k < 13; ++k) {
    int idx = idx0 + k;
    if (idx <= NB) {
      int e = laneoff + c[k];
      pairOffset[idx] = e;
      if (idx < NB) bucketCursor[idx] = e;
    }
  }
}

// Phase A: bucket-sort edges into pair[] (packed (s<<7)|dlocal)
__global__ __launch_bounds__(512) void kb_scatA(const int* __restrict__ ei,
                                                int* __restrict__ bucketCursor,
                                                int* __restrict__ pair) {
  __shared__ int lcnt[NB + 1];
  __shared__ int gbase[NB];
  __shared__ int lcur[NB];
  __shared__ int stage[ACHUNK];
  int tid = threadIdx.x;
  int e0 = blockIdx.x * ACHUNK;
  int n = min(ACHUNK, NE - e0);
  for (int i = tid; i <= NB; i += 512) lcnt[i] = 0;
  __syncthreads();
  for (int i = tid; i < n; i += 512) atomicAdd(&lcnt[ei[NE + e0 + i] >> 7], 1);
  __syncthreads();
  if (tid < 64) {  // wave-0 scan of lcnt -> exclusive (in place); lcnt[NB] = n
    int c[13];
    int run = 0;
    int idx0 = tid * 13;
#pragma unroll
    for (int k = 0; k < 13; ++k) {
      int idx = idx0 + k;
      int v = (idx < NB) ? lcnt[idx] : 0;
      c[k] = run;
      run += v;
    }
    int x = run;
#pragma unroll
    for (int d = 1; d < 64; d <<= 1) {
      int y = __shfl_up(x, d, 64);
      if (tid >= d) x += y;
    }
    int laneoff = x - run;
#pragma unroll
    for (int k = 0; k < 13; ++k) {
      int idx = idx0 + k;
      if (idx <= NB) lcnt[idx] = laneoff + c[k];
    }
  }
  __syncthreads();
  for (int b = tid; b < NB; b += 512) {
    int base = lcnt[b], cnt = lcnt[b + 1] - base;
    gbase[b] = cnt ? atomicAdd(&bucketCursor[b], cnt) : 0;
    lcur[b] = base;
  }
  __syncthreads();
  for (int i = tid; i < n; i += 512) {
    int s = ei[e0 + i], d = ei[NE + e0 + i];
    int b = d >> 7;
    int p = atomicAdd(&lcur[b], 1);
    stage[p] = (s << 7) | (d & 127);
  }
  __syncthreads();
  // copy-out: lane-per-bucket, each bucket's run is contiguous in pair[]
  for (int b = tid; b < NB; b += 512) {
    int base = lcnt[b], cnt = lcnt[b + 1] - base, g = gbase[b];
    for (int k = 0; k < cnt; ++k) pair[g + k] = stage[base + k];
  }
}

// Phase B: per bucket, exact CSR placement in LDS, coalesced col/rowptr writes
__global__ __launch_bounds__(256) void kb_binB(const int* __restrict__ pair,
                                               const int* __restrict__ pairOffset,
                                               int* __restrict__ rowptr,
                                               int* __restrict__ col) {
  __shared__ int cnt[128];
  __shared__ int cur[128];
  __shared__ int stage[BCAP];
  int tid = threadIdx.x;
  int b = blockIdx.x;
  int dbase = b << 7;
  int nd = min(128, NN - dbase);
  int pbeg = pairOffset[b], m = pairOffset[b + 1] - pbeg;
  int cbase = pbeg + dbase;  // +1 self-loop for every preceding dst
  if (tid < 128) cnt[tid] = 0;
  __syncthreads();
  for (int i = tid; i < m; i += 256) atomicAdd(&cnt[pair[pbeg + i] & 127], 1);
  __syncthreads();
  if (tid < 64) {  // scan 128 degree counters (2/lane), place self-loops
    int i0 = 2 * tid, i1 = 2 * tid + 1;
    int v0 = cnt[i0] + (i0 < nd ? 1 : 0);
    int v1 = cnt[i1] + (i1 < nd ? 1 : 0);
    int run = v0 + v1;
    int x = run;
#pragma unroll
    for (int d = 1; d < 64; d <<= 1) {
      int y = __shfl_up(x, d, 64);
      if (tid >= d) x += y;
    }
    int e0 = x - run;        // exclusive prefix for i0
    int e1 = e0 + v0;
    if (i0 < nd) { rowptr[dbase + i0] = cbase + e0; stage[e0] = dbase + i0; cur[i0] = e0 + 1; }
    else cur[i0] = e0;
    if (i1 < nd) { rowptr[dbase + i1] = cbase + e1; stage[e1] = dbase + i1; cur[i1] = e1 + 1; }
    else cur[i1] = e1;
  }
  if (b == NB - 1 && tid == 0) rowptr[NN] = NTOT;
  __syncthreads();
  for (int i = tid; i < m; i += 256) {
    int p = pair[pbeg + i];
    int pos = atomicAdd(&cur[p & 127], 1);
    stage[pos] = p >> 7;
  }
  __syncthreads();
  int tot = m + nd;
  for (int i = tid; i < tot; i += 256) col[cbase + i] = stage[i];
}

// ---------------- W1 hi/lo bf16 split (once) ----------------
__global__ void k_cvtW(const float* __restrict__ W1, unsigned short* __restrict__ Wh,
                       unsigned short* __restrict__ Wl) {
  int i = blockIdx.x * 256 + threadIdx.x;
  if (i < 128 * 128) {
    float v = W1[i];
    unsigned short h = f2bf(v);
    Wh[i] = h;
    Wl[i] = f2bf(v - blo((unsigned int)h));
  }
}

// ------- Layer 1 GEMM (fp32 via hi/lo MFMA) + fused attention coefs + bf16 h1 -------
__global__ __launch_bounds__(256) void k_gemm1(
    const float* __restrict__ x, const unsigned short* __restrict__ Wh,
    const unsigned short* __restrict__ Wl, const float* __restrict__ asrc,
    const float* __restrict__ adst, unsigned short* __restrict__ h1b,
    float4* __restrict__ as1, float4* __restrict__ ad1) {
  __shared__ unsigned short hstage[4][16][128];  // 16 KB: per-wave h1 tile
  int wid = threadIdx.x >> 6, lane = threadIdx.x & 63;
  int tile = blockIdx.x * 4 + wid;
  if (tile >= NN / 16) tile = NN / 16 - 1;  // clamp (duplicate work, benign; keeps barrier full)
  int r16 = lane & 15, quad = lane >> 4;
  const float* xrow = x + (size_t)(tile * 16 + r16) * 128 + quad * 8;
  bf16x8 ah[4], al[4];
#pragma unroll
  for (int c = 0; c < 4; ++c)
#pragma unroll
    for (int j = 0; j < 8; ++j) {
      float v = xrow[c * 32 + j];
      unsigned short h = f2bf(v);
      ah[c][j] = (short)h;
      al[c][j] = (short)f2bf(v - blo((unsigned int)h));
    }
  float asp[4][4], adp[4][4];
#pragma unroll
  for (int h = 0; h < 4; ++h)
#pragma unroll
    for (int r = 0; r < 4; ++r) { asp[h][r] = 0.f; adp[h][r] = 0.f; }
#pragma unroll
  for (int ot = 0; ot < 8; ++ot) {
    const bf16x8* whrow = (const bf16x8*)(Wh + (size_t)(ot * 16 + r16) * 128);
    const bf16x8* wlrow = (const bf16x8*)(Wl + (size_t)(ot * 16 + r16) * 128);
    f32x4 acc = {0.f, 0.f, 0.f, 0.f};
#pragma unroll
    for (int c = 0; c < 4; ++c) {
      bf16x8 wh = whrow[c * 4 + quad];
      bf16x8 wl = wlrow[c * 4 + quad];
      acc = __builtin_amdgcn_mfma_f32_16x16x32_bf16(ah[c], wh, acc, 0, 0, 0);
      acc = __builtin_amdgcn_mfma_f32_16x16x32_bf16(ah[c], wl, acc, 0, 0, 0);
      acc = __builtin_amdgcn_mfma_f32_16x16x32_bf16(al[c], wh, acc, 0, 0, 0);
    }
    float sa = asrc[ot * 16 + r16], da = adst[ot * 16 + r16];
    const int hh = ot >> 1;
#pragma unroll
    for (int r = 0; r < 4; ++r) {
      asp[hh][r] += acc[r] * sa;
      adp[hh][r] += acc[r] * da;
    }
    // stage bf16 tile in LDS: row = quad*4+r, col = ot*16+r16
    unsigned short* st = &hstage[wid][quad * 4][ot * 16 + r16];
    st[0] = f2bf(acc[0]); st[128] = f2bf(acc[1]);
    st[256] = f2bf(acc[2]); st[384] = f2bf(acc[3]);
  }
#pragma unroll
  for (int h = 0; h < 4; ++h)
#pragma unroll
    for (int r = 0; r < 4; ++r) {
      float v = asp[h][r];
      v += __shfl_xor(v, 1, 64); v += __shfl_xor(v, 2, 64);
      v += __shfl_xor(v, 4, 64); v += __shfl_xor(v, 8, 64);
      asp[h][r] = v;
      float w = adp[h][r];
      w += __shfl_xor(w, 1, 64); w += __shfl_xor(w, 2, 64);
      w += __shfl_xor(w, 4, 64); w += __shfl_xor(w, 8, 64);
      adp[h][r] = w;
    }
#pragma unroll
  for (int r = 0; r < 4; ++r) {
    if (r16 == r) {
      int node = tile * 16 + quad * 4 + r;
      as1[node] = make_float4(asp[0][r], asp[1][r], asp[2][r], asp[3][r]);
      ad1[node] = make_float4(adp[0][r], adp[1][r], adp[2][r], adp[3][r]);
    }
  }
  __syncthreads();
  // coalesced 16B copy-out of this wave's 4KB tile
  const uint4* src = (const uint4*)&hstage[wid][0][0];
  uint4* dst = (uint4*)(h1b + (size_t)tile * 16 * 128);
#pragma unroll
  for (int i = 0; i < 4; ++i) dst[i * 64 + lane] = src[i * 64 + lane];
}

// ------- layer-1 aggregation: producer/consumer shfl, bf16 gathers, fused L2 GEMM -------
__global__ __launch_bounds__(256, 8) void k_agg1(
    const unsigned short* __restrict__ h1b, const float* __restrict__ as1,
    const float* __restrict__ ad1, const int* __restrict__ rowptr,
    const int* __restrict__ col, const float* __restrict__ b1,
    const float* __restrict__ W2, const float* __restrict__ asrc2,
    const float* __restrict__ adst2, float4* __restrict__ node2) {
  int wid = threadIdx.x >> 6, lane = threadIdx.x & 63;
  int node = blockIdx.x * 4 + wid;           // exact: 25000*4 = NN
  int head = lane >> 4, k16 = lane & 15;
  int srcBase = lane & 48;                   // first lane of my head group
  float ad = ad1[node * 4 + head];
  int beg = rowptr[node], end = rowptr[node + 1];
  const unsigned int* h1u = (const unsigned int*)h1b;  // row stride 64 uints
  float accx = 0.f, accy = 0.f, wsum = 0.f;
  int j = beg;
  for (; j + 16 <= end; j += 16) {           // full batches: branch-free, 16-deep MLP
    int sP = col[j + k16];                   // producer: lane k16 owns edge j+k16
    float e = as1[sP * 4 + head] + ad;
    e = (e < 0.f) ? 0.2f * e : e;
    float wP = __expf(fminf(e, 80.f));
#pragma unroll
    for (int k = 0; k < 16; ++k) {
      float w = __shfl(wP, srcBase + k, 64);
      int s = __shfl(sP, srcBase + k, 64);
      unsigned int u = h1u[(size_t)s * 64 + lane];
      wsum += w;
      accx += w * blo(u);
      accy += w * bhi(u);
    }
  }
  int cnt = end - j;
  if (cnt > 0) {                             // remainder (<16 edges)
    int sP = col[min(j + k16, end - 1)];
    float e = as1[sP * 4 + head] + ad;
    e = (e < 0.f) ? 0.2f * e : e;
    float wP = __expf(fminf(e, 80.f));
    for (int k = 0; k < cnt; ++k) {
      float w = __shfl(wP, srcBase + k, 64);
      int s = __shfl(sP, srcBase + k, 64);
      unsigned int u = h1u[(size_t)s * 64 + lane];
      wsum += w;
      accx += w * blo(u);
      accy += w * bhi(u);
    }
  }
  float inv = 1.f / (wsum + 1e-16f);
  float hx = accx * inv + b1[2 * lane];
  float hy = accy * inv + b1[2 * lane + 1];
  hx = (hx < 0.f) ? 0.01f * hx : hx;
  hy = (hy < 0.f) ? 0.01f * hy : hy;
  float p0 = hx * W2[2 * lane] + hy * W2[2 * lane + 1];
  float p1 = hx * W2[128 + 2 * lane] + hy * W2[128 + 2 * lane + 1];
#pragma unroll
  for (int d = 1; d < 64; d <<= 1) {
    p0 += __shfl_xor(p0, d, 64);
    p1 += __shfl_xor(p1, d, 64);
  }
  if (lane == 0) {
    float as2 = p0 * asrc2[0] + p1 * asrc2[1];
    float ad2 = p0 * adst2[0] + p1 * adst2[1];
    node2[node] = make_float4(p0, p1, as2, ad2);
  }
}

// ---------------- layer-2 aggregation + log_softmax (4 lanes per node) ----------------
__global__ void k_agg2(const float4* __restrict__ node2, const int* __restrict__ rowptr,
                       const int* __restrict__ col, const float* __restrict__ b2,
                       float2* __restrict__ out) {
  int t = blockIdx.x * 256 + threadIdx.x;
  int node = t >> 2, sub = t & 3;
  if (node >= NN) return;
  float ad2 = node2[node].w;
  int beg = rowptr[node], end = rowptr[node + 1];
  float den = 0.f, a0 = 0.f, a1 = 0.f;
  for (int j = beg + sub; j < end; j += 4) {
    int s = col[j];
    float4 sv = node2[s];
    float e = sv.z + ad2;
    e = (e < 0.f) ? 0.2f * e : e;
    float w = __expf(fminf(e, 80.f));
    den += w;
    a0 += w * sv.x;
    a1 += w * sv.y;
  }
#pragma unroll
  for (int d = 1; d < 4; d <<= 1) {
    den += __shfl_xor(den, d, 64);
    a0 += __shfl_xor(a0, d, 64);
    a1 += __shfl_xor(a1, d, 64);
  }
  if (sub == 0) {
    float inv = 1.f / (den + 1e-16f);
    float o0 = a0 * inv + b2[0];
    float o1 = a1 * inv + b2[1];
    float m = fmaxf(o0, o1);
    float lse = m + __logf(__expf(o0 - m) + __expf(o1 - m));
    out[node] = make_float2(o0 - lse, o1 - lse);
  }
}

extern "C" void kernel_launch(void* const* d_in, const int* in_sizes, int n_in,
                              void* d_out, int out_size, void* d_ws, size_t ws_size,
                              hipStream_t stream) {
  const float* x     = (const float*)d_in[0];
  const int*   ei    = (const int*)d_in[1];
  const float* W1    = (const float*)d_in[2];
  const float* asrc1 = (const float*)d_in[3];
  const float* adst1 = (const float*)d_in[4];
  const float* b1    = (const float*)d_in[5];
  const float* W2    = (const float*)d_in[6];
  const float* asrc2 = (const float*)d_in[7];
  const float* adst2 = (const float*)d_in[8];
  const float* b2    = (const float*)d_in[9];
  float2* out = (float2*)d_out;

  // workspace layout
  int* rowptr       = (int*)d_ws;                  // 100352
  int* col          = rowptr + 100352;             // 1700096
  int* pair         = col + 1700096;               // 1600000
  int* bucketCnt    = pair + 1600000;              // 1024
  int* pairOffset   = bucketCnt + 1024;            // 1024
  int* bucketCursor = pairOffset + 1024;           // 1024
  unsigned short* h1b = (unsigned short*)(bucketCursor + 1024);  // NN*128 bf16
  float*  as1  = (float*)(h1b + (size_t)NN * 128); // NN*4
  float*  ad1  = as1 + NN * 4;                     // NN*4
  float4* node2 = (float4*)(ad1 + NN * 4);         // NN
  unsigned short* W1h = (unsigned short*)(node2 + NN);  // 16384
  unsigned short* W1l = W1h + 16384;                    // 16384

  k_zero<<<1, 1024, 0, stream>>>(bucketCnt);
  kb_hist<<<782, 256, 0, stream>>>(ei, bucketCnt);
  kb_scan<<<1, 64, 0, stream>>>(bucketCnt, pairOffset, bucketCursor);
  kb_scatA<<<(NE + ACHUNK - 1) / ACHUNK, 512, 0, stream>>>(ei, bucketCursor, pair);
  kb_binB<<<NB, 256, 0, stream>>>(pair, pairOffset, rowptr, col);
  k_cvtW<<<64, 256, 0, stream>>>(W1, W1h, W1l);
  k_gemm1<<<(NN / 16 + 3) / 4, 256, 0, stream>>>(x, W1h, W1l, asrc1, adst1, h1b,
                                                 (float4*)as1, (float4*)ad1);
  k_agg1<<<NN / 4, 256, 0, stream>>>(h1b, as1, ad1, rowptr, col, b1, W2, asrc2, adst2, node2);
  k_agg2<<<(NN * 4 + 255) / 256, 256, 0, stream>>>(node2, rowptr, col, b2, out);
}

// Round 7
// 290.445 us; speedup vs baseline: 2.3533x; 1.0903x over previous
//
#include <hip/hip_runtime.h>

#define NN 100000
#define NE 1600000
#define NTOT (NN + NE)
#define NB 782            // buckets of 128 dst nodes
#define ACHUNK 4096       // edges per phase-A block
#define BCAP 3072         // phase-B LDS col capacity

typedef __attribute__((ext_vector_type(8))) short bf16x8;
typedef __attribute__((ext_vector_type(4))) float f32x4;

static __device__ __forceinline__ float blo(unsigned int u) {
  union { unsigned int i; float f; } v; v.i = u << 16; return v.f;
}
static __device__ __forceinline__ float bhi(unsigned int u) {
  union { unsigned int i; float f; } v; v.i = u & 0xffff0000u; return v.f;
}
static __device__ __forceinline__ unsigned short f2bf(float f) {
  union { float f; unsigned int i; } v; v.f = f;
  unsigned int i = v.i;
  i += 0x7fffu + ((i >> 16) & 1u);
  return (unsigned short)(i >> 16);
}

// ---------------- CSR build: two-phase LDS-binned counting sort ----------------
__global__ void k_zero(int* __restrict__ bucketCnt) {
  int i = threadIdx.x;
  if (i < NB) bucketCnt[i] = 0;
}

__global__ __launch_bounds__(256) void kb_hist(const int* __restrict__ ei,
                                               int* __restrict__ bucketCnt) {
  __shared__ int h[NB];
  int tid = threadIdx.x;
  for (int i = tid; i < NB; i += 256) h[i] = 0;
  __syncthreads();
  for (int i = blockIdx.x * 256 + tid; i < NE; i += gridDim.x * 256)
    atomicAdd(&h[ei[NE + i] >> 7], 1);
  __syncthreads();
  for (int i = tid; i < NB; i += 256)
    if (h[i]) atomicAdd(&bucketCnt[i], h[i]);
}

__global__ void kb_scan(const int* __restrict__ bucketCnt, int* __restrict__ pairOffset,
                        int* __restrict__ bucketCursor) {
  int lane = threadIdx.x;  // 64 threads, 13 chunks each
  int c[13];
  int run = 0;
  int idx0 = lane * 13;
#pragma unroll
  for (int k = 0; k < 13; ++k) {
    int idx = idx0 + k;
    int v = (idx < NB) ? bucketCnt[idx] : 0;
    c[k] = run;
    run += v;
  }
  int x = run;
#pragma unroll
  for (int d = 1; d < 64; d <<= 1) {
    int y = __shfl_up(x, d, 64);
    if (lane >= d) x += y;
  }
  int laneoff = x - run;
#pragma unroll
  for (int k = 0; k < 13; ++k) {
    int idx = idx0 + k;
    if (idx <= NB) {
      int e = laneoff + c[k];
      pairOffset[idx] = e;
      if (idx < NB) bucketCursor[idx] = e;
    }
  }
}

__global__ __launch_bounds__(512) void kb_scatA(const int* __restrict__ ei,
                                                int* __restrict__ bucketCursor,
                                                int* __restrict__ pair) {
  __shared__ int lcnt[NB + 1];
  __shared__ int gbase[NB];
  __shared__ int lcur[NB];
  __shared__ int stage[ACHUNK];
  int tid = threadIdx.x;
  int e0 = blockIdx.x * ACHUNK;
  int n = min(ACHUNK, NE - e0);
  for (int i = tid; i <= NB; i += 512) lcnt[i] = 0;
  __syncthreads();
  for (int i = tid; i < n; i += 512) atomicAdd(&lcnt[ei[NE + e0 + i] >> 7], 1);
  __syncthreads();
  if (tid < 64) {
    int c[13];
    int run = 0;
    int idx0 = tid * 13;
#pragma unroll
    for (int k = 0; k < 13; ++k) {
      int idx = idx0 + k;
      int v = (idx < NB) ? lcnt[idx] : 0;
      c[k] = run;
      run += v;
    }
    int x = run;
#pragma unroll
    for (int d = 1; d < 64; d <<= 1) {
      int y = __shfl_up(x, d, 64);
      if (tid >= d) x += y;
    }
    int laneoff = x - run;
#pragma unroll
    for (int k = 0; k < 13; ++k) {
      int idx = idx0 + k;
      if (idx <= NB) lcnt[idx] = laneoff + c[k];
    }
  }
  __syncthreads();
  for (int b = tid; b < NB; b += 512) {
    int base = lcnt[b], cnt = lcnt[b + 1] - base;
    gbase[b] = cnt ? atomicAdd(&bucketCursor[b], cnt) : 0;
    lcur[b] = base;
  }
  __syncthreads();
  for (int i = tid; i < n; i += 512) {
    int s = ei[e0 + i], d = ei[NE + e0 + i];
    int b = d >> 7;
    int p = atomicAdd(&lcur[b], 1);
    stage[p] = (s << 7) | (d & 127);
  }
  __syncthreads();
  for (int b = tid; b < NB; b += 512) {
    int base = lcnt[b], cnt = lcnt[b + 1] - base, g = gbase[b];
    for (int k = 0; k < cnt; ++k) pair[g + k] = stage[base + k];
  }
}

__global__ __launch_bounds__(256) void kb_binB(const int* __restrict__ pair,
                                               const int* __restrict__ pairOffset,
                                               int* __restrict__ rowptr,
                                               int* __restrict__ col) {
  __shared__ int cnt[128];
  __shared__ int cur[128];
  __shared__ int stage[BCAP];
  int tid = threadIdx.x;
  int b = blockIdx.x;
  int dbase = b << 7;
  int nd = min(128, NN - dbase);
  int pbeg = pairOffset[b], m = pairOffset[b + 1] - pbeg;
  int cbase = pbeg + dbase;
  if (tid < 128) cnt[tid] = 0;
  __syncthreads();
  for (int i = tid; i < m; i += 256) atomicAdd(&cnt[pair[pbeg + i] & 127], 1);
  __syncthreads();
  if (tid < 64) {
    int i0 = 2 * tid, i1 = 2 * tid + 1;
    int v0 = cnt[i0] + (i0 < nd ? 1 : 0);
    int v1 = cnt[i1] + (i1 < nd ? 1 : 0);
    int run = v0 + v1;
    int x = run;
#pragma unroll
    for (int d = 1; d < 64; d <<= 1) {
      int y = __shfl_up(x, d, 64);
      if (tid >= d) x += y;
    }
    int e0 = x - run;
    int e1 = e0 + v0;
    if (i0 < nd) { rowptr[dbase + i0] = cbase + e0; stage[e0] = dbase + i0; cur[i0] = e0 + 1; }
    else cur[i0] = e0;
    if (i1 < nd) { rowptr[dbase + i1] = cbase + e1; stage[e1] = dbase + i1; cur[i1] = e1 + 1; }
    else cur[i1] = e1;
  }
  if (b == NB - 1 && tid == 0) rowptr[NN] = NTOT;
  __syncthreads();
  for (int i = tid; i < m; i += 256) {
    int p = pair[pbeg + i];
    int pos = atomicAdd(&cur[p & 127], 1);
    stage[pos] = p >> 7;
  }
  __syncthreads();
  int tot = m + nd;
  for (int i = tid; i < tot; i += 256) col[cbase + i] = stage[i];
}

// ---------------- W1 hi/lo bf16 split (once) ----------------
__global__ void k_cvtW(const float* __restrict__ W1, unsigned short* __restrict__ Wh,
                       unsigned short* __restrict__ Wl) {
  int i = blockIdx.x * 256 + threadIdx.x;
  if (i < 128 * 128) {
    float v = W1[i];
    unsigned short h = f2bf(v);
    Wh[i] = h;
    Wl[i] = f2bf(v - blo((unsigned int)h));
  }
}

// ------- Layer 1 GEMM (fp32 via hi/lo MFMA) + fused attention coefs + bf16 h1 -------
__global__ __launch_bounds__(256) void k_gemm1(
    const float* __restrict__ x, const unsigned short* __restrict__ Wh,
    const unsigned short* __restrict__ Wl, const float* __restrict__ asrc,
    const float* __restrict__ adst, unsigned short* __restrict__ h1b,
    float4* __restrict__ as1, float4* __restrict__ ad1) {
  __shared__ unsigned short hstage[4][16][128];  // 16 KB: per-wave h1 tile
  int wid = threadIdx.x >> 6, lane = threadIdx.x & 63;
  int tile = blockIdx.x * 4 + wid;
  if (tile >= NN / 16) tile = NN / 16 - 1;  // clamp; keeps barrier full
  int r16 = lane & 15, quad = lane >> 4;
  const float* xrow = x + (size_t)(tile * 16 + r16) * 128 + quad * 8;
  bf16x8 ah[4], al[4];
#pragma unroll
  for (int c = 0; c < 4; ++c)
#pragma unroll
    for (int j = 0; j < 8; ++j) {
      float v = xrow[c * 32 + j];
      unsigned short h = f2bf(v);
      ah[c][j] = (short)h;
      al[c][j] = (short)f2bf(v - blo((unsigned int)h));
    }
  float asp[4][4], adp[4][4];
#pragma unroll
  for (int h = 0; h < 4; ++h)
#pragma unroll
    for (int r = 0; r < 4; ++r) { asp[h][r] = 0.f; adp[h][r] = 0.f; }
#pragma unroll
  for (int ot = 0; ot < 8; ++ot) {
    const bf16x8* whrow = (const bf16x8*)(Wh + (size_t)(ot * 16 + r16) * 128);
    const bf16x8* wlrow = (const bf16x8*)(Wl + (size_t)(ot * 16 + r16) * 128);
    f32x4 acc = {0.f, 0.f, 0.f, 0.f};
#pragma unroll
    for (int c = 0; c < 4; ++c) {
      bf16x8 wh = whrow[c * 4 + quad];
      bf16x8 wl = wlrow[c * 4 + quad];
      acc = __builtin_amdgcn_mfma_f32_16x16x32_bf16(ah[c], wh, acc, 0, 0, 0);
      acc = __builtin_amdgcn_mfma_f32_16x16x32_bf16(ah[c], wl, acc, 0, 0, 0);
      acc = __builtin_amdgcn_mfma_f32_16x16x32_bf16(al[c], wh, acc, 0, 0, 0);
    }
    float sa = asrc[ot * 16 + r16], da = adst[ot * 16 + r16];
    const int hh = ot >> 1;
#pragma unroll
    for (int r = 0; r < 4; ++r) {
      asp[hh][r] += acc[r] * sa;
      adp[hh][r] += acc[r] * da;
    }
    unsigned short* st = &hstage[wid][quad * 4][ot * 16 + r16];
    st[0] = f2bf(acc[0]); st[128] = f2bf(acc[1]);
    st[256] = f2bf(acc[2]); st[384] = f2bf(acc[3]);
  }
#pragma unroll
  for (int h = 0; h < 4; ++h)
#pragma unroll
    for (int r = 0; r < 4; ++r) {
      float v = asp[h][r];
      v += __shfl_xor(v, 1, 64); v += __shfl_xor(v, 2, 64);
      v += __shfl_xor(v, 4, 64); v += __shfl_xor(v, 8, 64);
      asp[h][r] = v;
      float w = adp[h][r];
      w += __shfl_xor(w, 1, 64); w += __shfl_xor(w, 2, 64);
      w += __shfl_xor(w, 4, 64); w += __shfl_xor(w, 8, 64);
      adp[h][r] = w;
    }
#pragma unroll
  for (int r = 0; r < 4; ++r) {
    if (r16 == r) {
      int node = tile * 16 + quad * 4 + r;
      as1[node] = make_float4(asp[0][r], asp[1][r], asp[2][r], asp[3][r]);
      ad1[node] = make_float4(adp[0][r], adp[1][r], adp[2][r], adp[3][r]);
    }
  }
  __syncthreads();
  const uint4* src = (const uint4*)&hstage[wid][0][0];
  uint4* dst = (uint4*)(h1b + (size_t)tile * 16 * 128);
#pragma unroll
  for (int i = 0; i < 4; ++i) dst[i * 64 + lane] = src[i * 64 + lane];
}

// ------- layer-1 aggregation: 4 nodes/wave, 16 lanes/node, uint4 gathers (4x MLP) -------
__global__ __launch_bounds__(256, 8) void k_agg1(
    const unsigned short* __restrict__ h1b, const float* __restrict__ as1,
    const float* __restrict__ ad1, const int* __restrict__ rowptr,
    const int* __restrict__ col, const float* __restrict__ b1,
    const float* __restrict__ W2, const float* __restrict__ asrc2,
    const float* __restrict__ adst2, float4* __restrict__ node2) {
  int wid = threadIdx.x >> 6, lane = threadIdx.x & 63;
  int grp = lane >> 4, l16 = lane & 15;
  int node = blockIdx.x * 16 + wid * 4 + grp;   // exact: 6250*16 = NN
  int head = l16 >> 2;                          // channels [l16*8, l16*8+8)
  float ad = ad1[node * 4 + head];
  int beg = rowptr[node], deg = rowptr[node + 1] - beg;
  const uint4* h1q = (const uint4*)h1b;         // row stride 16 uint4
  float acc[8] = {0.f, 0.f, 0.f, 0.f, 0.f, 0.f, 0.f, 0.f};
  float wsum = 0.f;
  int j = 0;
  while (__ballot(j < deg)) {
    // 4 predicated edges per group; all loads independent -> up to 16 gathers/wave in flight
    bool a[4]; int s[4];
#pragma unroll
    for (int k = 0; k < 4; ++k) {
      a[k] = (j + k) < deg;
      s[k] = a[k] ? col[beg + j + k] : 0;
    }
    float e[4]; uint4 u[4];
#pragma unroll
    for (int k = 0; k < 4; ++k) e[k] = as1[s[k] * 4 + head] + ad;
#pragma unroll
    for (int k = 0; k < 4; ++k) u[k] = h1q[(size_t)s[k] * 16 + l16];
#pragma unroll
    for (int k = 0; k < 4; ++k) {
      float t = e[k];
      t = (t < 0.f) ? 0.2f * t : t;
      float w = a[k] ? __expf(fminf(t, 80.f)) : 0.f;
      wsum += w;
      acc[0] += w * blo(u[k].x); acc[1] += w * bhi(u[k].x);
      acc[2] += w * blo(u[k].y); acc[3] += w * bhi(u[k].y);
      acc[4] += w * blo(u[k].z); acc[5] += w * bhi(u[k].z);
      acc[6] += w * blo(u[k].w); acc[7] += w * bhi(u[k].w);
    }
    j += 4;
  }
  float inv = 1.f / (wsum + 1e-16f);
  int cb = l16 * 8;
  float h[8];
#pragma unroll
  for (int t = 0; t < 8; ++t) {
    float v = acc[t] * inv + b1[cb + t];
    h[t] = (v < 0.f) ? 0.01f * v : v;
  }
  float p0 = 0.f, p1 = 0.f;
#pragma unroll
  for (int t = 0; t < 8; ++t) {
    p0 += h[t] * W2[cb + t];
    p1 += h[t] * W2[128 + cb + t];
  }
  // reduce across the 16 lanes of this group (masks 1,2,4,8 stay in-group)
  p0 += __shfl_xor(p0, 1, 64); p0 += __shfl_xor(p0, 2, 64);
  p0 += __shfl_xor(p0, 4, 64); p0 += __shfl_xor(p0, 8, 64);
  p1 += __shfl_xor(p1, 1, 64); p1 += __shfl_xor(p1, 2, 64);
  p1 += __shfl_xor(p1, 4, 64); p1 += __shfl_xor(p1, 8, 64);
  if (l16 == 0) {
    float as2 = p0 * asrc2[0] + p1 * asrc2[1];
    float ad2 = p0 * adst2[0] + p1 * adst2[1];
    node2[node] = make_float4(p0, p1, as2, ad2);
  }
}

// ---------------- layer-2 aggregation + log_softmax (4 lanes per node) ----------------
__global__ void k_agg2(const float4* __restrict__ node2, const int* __restrict__ rowptr,
                       const int* __restrict__ col, const float* __restrict__ b2,
                       float2* __restrict__ out) {
  int t = blockIdx.x * 256 + threadIdx.x;
  int node = t >> 2, sub = t & 3;
  if (node >= NN) return;
  float ad2 = node2[node].w;
  int beg = rowptr[node], end = rowptr[node + 1];
  float den = 0.f, a0 = 0.f, a1 = 0.f;
  for (int j = beg + sub; j < end; j += 4) {
    int s = col[j];
    float4 sv = node2[s];
    float e = sv.z + ad2;
    e = (e < 0.f) ? 0.2f * e : e;
    float w = __expf(fminf(e, 80.f));
    den += w;
    a0 += w * sv.x;
    a1 += w * sv.y;
  }
#pragma unroll
  for (int d = 1; d < 4; d <<= 1) {
    den += __shfl_xor(den, d, 64);
    a0 += __shfl_xor(a0, d, 64);
    a1 += __shfl_xor(a1, d, 64);
  }
  if (sub == 0) {
    float inv = 1.f / (den + 1e-16f);
    float o0 = a0 * inv + b2[0];
    float o1 = a1 * inv + b2[1];
    float m = fmaxf(o0, o1);
    float lse = m + __logf(__expf(o0 - m) + __expf(o1 - m));
    out[node] = make_float2(o0 - lse, o1 - lse);
  }
}

extern "C" void kernel_launch(void* const* d_in, const int* in_sizes, int n_in,
                              void* d_out, int out_size, void* d_ws, size_t ws_size,
                              hipStream_t stream) {
  const float* x     = (const float*)d_in[0];
  const int*   ei    = (const int*)d_in[1];
  const float* W1    = (const float*)d_in[2];
  const float* asrc1 = (const float*)d_in[3];
  const float* adst1 = (const float*)d_in[4];
  const float* b1    = (const float*)d_in[5];
  const float* W2    = (const float*)d_in[6];
  const float* asrc2 = (const float*)d_in[7];
  const float* adst2 = (const float*)d_in[8];
  const float* b2    = (const float*)d_in[9];
  float2* out = (float2*)d_out;

  int* rowptr       = (int*)d_ws;                  // 100352
  int* col          = rowptr + 100352;             // 1700096
  int* pair         = col + 1700096;               // 1600000
  int* bucketCnt    = pair + 1600000;              // 1024
  int* pairOffset   = bucketCnt + 1024;            // 1024
  int* bucketCursor = pairOffset + 1024;           // 1024
  unsigned short* h1b = (unsigned short*)(bucketCursor + 1024);  // NN*128 bf16
  float*  as1  = (float*)(h1b + (size_t)NN * 128); // NN*4
  float*  ad1  = as1 + NN * 4;                     // NN*4
  float4* node2 = (float4*)(ad1 + NN * 4);         // NN
  unsigned short* W1h = (unsigned short*)(node2 + NN);  // 16384
  unsigned short* W1l = W1h + 16384;                    // 16384

  k_zero<<<1, 1024, 0, stream>>>(bucketCnt);
  kb_hist<<<782, 256, 0, stream>>>(ei, bucketCnt);
  kb_scan<<<1, 64, 0, stream>>>(bucketCnt, pairOffset, bucketCursor);
  kb_scatA<<<(NE + ACHUNK - 1) / ACHUNK, 512, 0, stream>>>(ei, bucketCursor, pair);
  kb_binB<<<NB, 256, 0, stream>>>(pair, pairOffset, rowptr, col);
  k_cvtW<<<64, 256, 0, stream>>>(W1, W1h, W1l);
  k_gemm1<<<(NN / 16 + 3) / 4, 256, 0, stream>>>(x, W1h, W1l, asrc1, adst1, h1b,
                                                 (float4*)as1, (float4*)ad1);
  k_agg1<<<NN / 16, 256, 0, stream>>>(h1b, as1, ad1, rowptr, col, b1, W2, asrc2, adst2, node2);
  k_agg2<<<(NN * 4 + 255) / 256, 256, 0, stream>>>(node2, rowptr, col, b2, out);
}

// Round 8
// 275.579 us; speedup vs baseline: 2.4803x; 1.0539x over previous
//
#include <hip/hip_runtime.h>

#define NN 100000
#define NE 1600000
#define NTOT (NN + NE)
#define NB 782            // buckets of 128 dst nodes
#define ACHUNK 4096       // edges per chunk (hist/scatA block)
#define NCH 391           // number of chunks = ceil(NE/ACHUNK)
#define BCAP 3072         // phase-B LDS col capacity

typedef __attribute__((ext_vector_type(8))) short bf16x8;
typedef __attribute__((ext_vector_type(4))) float f32x4;

static __device__ __forceinline__ float blo(unsigned int u) {
  union { unsigned int i; float f; } v; v.i = u << 16; return v.f;
}
static __device__ __forceinline__ float bhi(unsigned int u) {
  union { unsigned int i; float f; } v; v.i = u & 0xffff0000u; return v.f;
}
static __device__ __forceinline__ unsigned short f2bf(float f) {
  union { float f; unsigned int i; } v; v.f = f;
  unsigned int i = v.i;
  i += 0x7fffu + ((i >> 16) & 1u);
  return (unsigned short)(i >> 16);
}

// ---------------- CSR build: atomic-free two-phase counting sort ----------------
// per-chunk bucket histogram -> cntMat[chunk][NB] (coalesced stores, no global atomics)
__global__ __launch_bounds__(512) void kb_hist(const int* __restrict__ ei,
                                               int* __restrict__ cntMat) {
  __shared__ int h[NB];
  int tid = threadIdx.x, blk = blockIdx.x;
  int e0 = blk * ACHUNK;
  int n = min(ACHUNK, NE - e0);
  for (int i = tid; i < NB; i += 512) h[i] = 0;
  __syncthreads();
  for (int i = tid; i < n; i += 512) atomicAdd(&h[ei[NE + e0 + i] >> 7], 1);
  __syncthreads();
  for (int i = tid; i < NB; i += 512) cntMat[blk * NB + i] = h[i];
}

// per bucket: exclusive scan down the chunk axis; bucketCnt[b] = column total
__global__ void kb_colscan(int* __restrict__ cntMat, int* __restrict__ bucketCnt) {
  int b = blockIdx.x;
  int lane = threadIdx.x;  // 64
  int carry = 0;
  for (int base = 0; base < NCH; base += 64) {
    int idx = base + lane;
    int v = (idx < NCH) ? cntMat[idx * NB + b] : 0;
    int x = v;
#pragma unroll
    for (int d = 1; d < 64; d <<= 1) {
      int y = __shfl_up(x, d, 64);
      if (lane >= d) x += y;
    }
    if (idx < NCH) cntMat[idx * NB + b] = carry + x - v;  // exclusive within column
    carry += __shfl(x, 63, 64);
  }
  if (lane == 0) bucketCnt[b] = carry;
}

// single-wave exclusive scan of NB totals -> pairOffset[0..NB]
__global__ void kb_scan(const int* __restrict__ bucketCnt, int* __restrict__ pairOffset) {
  int lane = threadIdx.x;  // 64 threads, 13 chunks each
  int c[13];
  int run = 0;
  int idx0 = lane * 13;
#pragma unroll
  for (int k = 0; k < 13; ++k) {
    int idx = idx0 + k;
    int v = (idx < NB) ? bucketCnt[idx] : 0;
    c[k] = run;
    run += v;
  }
  int x = run;
#pragma unroll
  for (int d = 1; d < 64; d <<= 1) {
    int y = __shfl_up(x, d, 64);
    if (lane >= d) x += y;
  }
  int laneoff = x - run;
#pragma unroll
  for (int k = 0; k < 13; ++k) {
    int idx = idx0 + k;
    if (idx <= NB) pairOffset[idx] = laneoff + c[k];
  }
}

// Phase A: bucket-sort chunk into pair[] (packed (s<<7)|dlocal); offsets precomputed
__global__ __launch_bounds__(512) void kb_scatA(const int* __restrict__ ei,
                                                const int* __restrict__ pairOffset,
                                                const int* __restrict__ cntMat,
                                                int* __restrict__ pair) {
  __shared__ int lcnt[NB + 1];
  __shared__ int gbase[NB];
  __shared__ int lcur[NB];
  __shared__ int stage[ACHUNK];
  int tid = threadIdx.x, blk = blockIdx.x;
  int e0 = blk * ACHUNK;
  int n = min(ACHUNK, NE - e0);
  for (int i = tid; i <= NB; i += 512) lcnt[i] = 0;
  __syncthreads();
  for (int i = tid; i < n; i += 512) atomicAdd(&lcnt[ei[NE + e0 + i] >> 7], 1);
  __syncthreads();
  if (tid < 64) {  // wave-0 scan of lcnt -> exclusive (in place); lcnt[NB] = n
    int c[13];
    int run = 0;
    int idx0 = tid * 13;
#pragma unroll
    for (int k = 0; k < 13; ++k) {
      int idx = idx0 + k;
      int v = (idx < NB) ? lcnt[idx] : 0;
      c[k] = run;
      run += v;
    }
    int x = run;
#pragma unroll
    for (int d = 1; d < 64; d <<= 1) {
      int y = __shfl_up(x, d, 64);
      if (tid >= d) x += y;
    }
    int laneoff = x - run;
#pragma unroll
    for (int k = 0; k < 13; ++k) {
      int idx = idx0 + k;
      if (idx <= NB) lcnt[idx] = laneoff + c[k];
    }
  }
  __syncthreads();
  for (int b = tid; b < NB; b += 512) {
    gbase[b] = pairOffset[b] + cntMat[blk * NB + b];  // no atomics
    lcur[b] = lcnt[b];
  }
  __syncthreads();
  for (int i = tid; i < n; i += 512) {
    int s = ei[e0 + i], d = ei[NE + e0 + i];
    int b = d >> 7;
    int p = atomicAdd(&lcur[b], 1);   // LDS only
    stage[p] = (s << 7) | (d & 127);
  }
  __syncthreads();
  for (int b = tid; b < NB; b += 512) {
    int base = lcnt[b], cnt = lcnt[b + 1] - base, g = gbase[b];
    for (int k = 0; k < cnt; ++k) pair[g + k] = stage[base + k];
  }
}

// Phase B: per bucket, exact CSR placement in LDS, coalesced col/rowptr writes
__global__ __launch_bounds__(256) void kb_binB(const int* __restrict__ pair,
                                               const int* __restrict__ pairOffset,
                                               int* __restrict__ rowptr,
                                               int* __restrict__ col) {
  __shared__ int cnt[128];
  __shared__ int cur[128];
  __shared__ int stage[BCAP];
  int tid = threadIdx.x;
  int b = blockIdx.x;
  int dbase = b << 7;
  int nd = min(128, NN - dbase);
  int pbeg = pairOffset[b], m = pairOffset[b + 1] - pbeg;
  int cbase = pbeg + dbase;
  if (tid < 128) cnt[tid] = 0;
  __syncthreads();
  for (int i = tid; i < m; i += 256) atomicAdd(&cnt[pair[pbeg + i] & 127], 1);
  __syncthreads();
  if (tid < 64) {
    int i0 = 2 * tid, i1 = 2 * tid + 1;
    int v0 = cnt[i0] + (i0 < nd ? 1 : 0);
    int v1 = cnt[i1] + (i1 < nd ? 1 : 0);
    int run = v0 + v1;
    int x = run;
#pragma unroll
    for (int d = 1; d < 64; d <<= 1) {
      int y = __shfl_up(x, d, 64);
      if (tid >= d) x += y;
    }
    int e0 = x - run;
    int e1 = e0 + v0;
    if (i0 < nd) { rowptr[dbase + i0] = cbase + e0; stage[e0] = dbase + i0; cur[i0] = e0 + 1; }
    else cur[i0] = e0;
    if (i1 < nd) { rowptr[dbase + i1] = cbase + e1; stage[e1] = dbase + i1; cur[i1] = e1 + 1; }
    else cur[i1] = e1;
  }
  if (b == NB - 1 && tid == 0) rowptr[NN] = NTOT;
  __syncthreads();
  for (int i = tid; i < m; i += 256) {
    int p = pair[pbeg + i];
    int pos = atomicAdd(&cur[p & 127], 1);
    stage[pos] = p >> 7;
  }
  __syncthreads();
  int tot = m + nd;
  for (int i = tid; i < tot; i += 256) col[cbase + i] = stage[i];
}

// ---------------- W1 hi/lo bf16 split (once) ----------------
__global__ void k_cvtW(const float* __restrict__ W1, unsigned short* __restrict__ Wh,
                       unsigned short* __restrict__ Wl) {
  int i = blockIdx.x * 256 + threadIdx.x;
  if (i < 128 * 128) {
    float v = W1[i];
    unsigned short h = f2bf(v);
    Wh[i] = h;
    Wl[i] = f2bf(v - blo((unsigned int)h));
  }
}

// ------- Layer 1 GEMM (fp32 via hi/lo MFMA) + fused attention coefs + bf16 h1 -------
__global__ __launch_bounds__(256) void k_gemm1(
    const float* __restrict__ x, const unsigned short* __restrict__ Wh,
    const unsigned short* __restrict__ Wl, const float* __restrict__ asrc,
    const float* __restrict__ adst, unsigned short* __restrict__ h1b,
    float4* __restrict__ as1, float4* __restrict__ ad1) {
  __shared__ unsigned short hstage[4][16][128];  // 16 KB: per-wave h1 tile
  int wid = threadIdx.x >> 6, lane = threadIdx.x & 63;
  int tile = blockIdx.x * 4 + wid;
  if (tile >= NN / 16) tile = NN / 16 - 1;  // clamp; keeps barrier full
  int r16 = lane & 15, quad = lane >> 4;
  const float* xrow = x + (size_t)(tile * 16 + r16) * 128 + quad * 8;
  bf16x8 ah[4], al[4];
#pragma unroll
  for (int c = 0; c < 4; ++c)
#pragma unroll
    for (int j = 0; j < 8; ++j) {
      float v = xrow[c * 32 + j];
      unsigned short h = f2bf(v);
      ah[c][j] = (short)h;
      al[c][j] = (short)f2bf(v - blo((unsigned int)h));
    }
  float asp[4][4], adp[4][4];
#pragma unroll
  for (int h = 0; h < 4; ++h)
#pragma unroll
    for (int r = 0; r < 4; ++r) { asp[h][r] = 0.f; adp[h][r] = 0.f; }
#pragma unroll
  for (int ot = 0; ot < 8; ++ot) {
    const bf16x8* whrow = (const bf16x8*)(Wh + (size_t)(ot * 16 + r16) * 128);
    const bf16x8* wlrow = (const bf16x8*)(Wl + (size_t)(ot * 16 + r16) * 128);
    f32x4 acc = {0.f, 0.f, 0.f, 0.f};
#pragma unroll
    for (int c = 0; c < 4; ++c) {
      bf16x8 wh = whrow[c * 4 + quad];
      bf16x8 wl = wlrow[c * 4 + quad];
      acc = __builtin_amdgcn_mfma_f32_16x16x32_bf16(ah[c], wh, acc, 0, 0, 0);
      acc = __builtin_amdgcn_mfma_f32_16x16x32_bf16(ah[c], wl, acc, 0, 0, 0);
      acc = __builtin_amdgcn_mfma_f32_16x16x32_bf16(al[c], wh, acc, 0, 0, 0);
    }
    float sa = asrc[ot * 16 + r16], da = adst[ot * 16 + r16];
    const int hh = ot >> 1;
#pragma unroll
    for (int r = 0; r < 4; ++r) {
      asp[hh][r] += acc[r] * sa;
      adp[hh][r] += acc[r] * da;
    }
    unsigned short* st = &hstage[wid][quad * 4][ot * 16 + r16];
    st[0] = f2bf(acc[0]); st[128] = f2bf(acc[1]);
    st[256] = f2bf(acc[2]); st[384] = f2bf(acc[3]);
  }
#pragma unroll
  for (int h = 0; h < 4; ++h)
#pragma unroll
    for (int r = 0; r < 4; ++r) {
      float v = asp[h][r];
      v += __shfl_xor(v, 1, 64); v += __shfl_xor(v, 2, 64);
      v += __shfl_xor(v, 4, 64); v += __shfl_xor(v, 8, 64);
      asp[h][r] = v;
      float w = adp[h][r];
      w += __shfl_xor(w, 1, 64); w += __shfl_xor(w, 2, 64);
      w += __shfl_xor(w, 4, 64); w += __shfl_xor(w, 8, 64);
      adp[h][r] = w;
    }
#pragma unroll
  for (int r = 0; r < 4; ++r) {
    if (r16 == r) {
      int node = tile * 16 + quad * 4 + r;
      as1[node] = make_float4(asp[0][r], asp[1][r], asp[2][r], asp[3][r]);
      ad1[node] = make_float4(adp[0][r], adp[1][r], adp[2][r], adp[3][r]);
    }
  }
  __syncthreads();
  const uint4* src = (const uint4*)&hstage[wid][0][0];
  uint4* dst = (uint4*)(h1b + (size_t)tile * 16 * 128);
#pragma unroll
  for (int i = 0; i < 4; ++i) dst[i * 64 + lane] = src[i * 64 + lane];
}

// ------- layer-1 aggregation: 4 nodes/wave, 16 lanes/node, uint4 gathers, unroll-8 -------
__global__ __launch_bounds__(256, 6) void k_agg1(
    const unsigned short* __restrict__ h1b, const float* __restrict__ as1,
    const float* __restrict__ ad1, const int* __restrict__ rowptr,
    const int* __restrict__ col, const float* __restrict__ b1,
    const float* __restrict__ W2, const float* __restrict__ asrc2,
    const float* __restrict__ adst2, float4* __restrict__ node2) {
  int wid = threadIdx.x >> 6, lane = threadIdx.x & 63;
  int grp = lane >> 4, l16 = lane & 15;
  int node = blockIdx.x * 16 + wid * 4 + grp;   // exact: 6250*16 = NN
  int head = l16 >> 2;
  float ad = ad1[node * 4 + head];
  int beg = rowptr[node], deg = rowptr[node + 1] - beg;
  const uint4* h1q = (const uint4*)h1b;         // row stride 16 uint4
  float acc[8] = {0.f, 0.f, 0.f, 0.f, 0.f, 0.f, 0.f, 0.f};
  float wsum = 0.f;
  int j = 0;
  while (__ballot(j < deg)) {
    // 8 predicated edges per group; inactive lanes gather row 0 (L2-hot, no HBM bytes)
    bool a[8]; int s[8];
#pragma unroll
    for (int k = 0; k < 8; ++k) {
      a[k] = (j + k) < deg;
      s[k] = a[k] ? col[beg + j + k] : 0;
    }
    float e[8]; uint4 u[8];
#pragma unroll
    for (int k = 0; k < 8; ++k) e[k] = as1[s[k] * 4 + head] + ad;
#pragma unroll
    for (int k = 0; k < 8; ++k) u[k] = h1q[(size_t)s[k] * 16 + l16];
#pragma unroll
    for (int k = 0; k < 8; ++k) {
      float t = e[k];
      t = (t < 0.f) ? 0.2f * t : t;
      float w = a[k] ? __expf(fminf(t, 80.f)) : 0.f;
      wsum += w;
      acc[0] += w * blo(u[k].x); acc[1] += w * bhi(u[k].x);
      acc[2] += w * blo(u[k].y); acc[3] += w * bhi(u[k].y);
      acc[4] += w * blo(u[k].z); acc[5] += w * bhi(u[k].z);
      acc[6] += w * blo(u[k].w); acc[7] += w * bhi(u[k].w);
    }
    j += 8;
  }
  float inv = 1.f / (wsum + 1e-16f);
  int cb = l16 * 8;
  float h[8];
#pragma unroll
  for (int t = 0; t < 8; ++t) {
    float v = acc[t] * inv + b1[cb + t];
    h[t] = (v < 0.f) ? 0.01f * v : v;
  }
  float p0 = 0.f, p1 = 0.f;
#pragma unroll
  for (int t = 0; t < 8; ++t) {
    p0 += h[t] * W2[cb + t];
    p1 += h[t] * W2[128 + cb + t];
  }
  p0 += __shfl_xor(p0, 1, 64); p0 += __shfl_xor(p0, 2, 64);
  p0 += __shfl_xor(p0, 4, 64); p0 += __shfl_xor(p0, 8, 64);
  p1 += __shfl_xor(p1, 1, 64); p1 += __shfl_xor(p1, 2, 64);
  p1 += __shfl_xor(p1, 4, 64); p1 += __shfl_xor(p1, 8, 64);
  if (l16 == 0) {
    float as2 = p0 * asrc2[0] + p1 * asrc2[1];
    float ad2 = p0 * adst2[0] + p1 * adst2[1];
    node2[node] = make_float4(p0, p1, as2, ad2);
  }
}

// ---------------- layer-2 aggregation + log_softmax (4 lanes per node) ----------------
__global__ void k_agg2(const float4* __restrict__ node2, const int* __restrict__ rowptr,
                       const int* __restrict__ col, const float* __restrict__ b2,
                       float2* __restrict__ out) {
  int t = blockIdx.x * 256 + threadIdx.x;
  int node = t >> 2, sub = t & 3;
  if (node >= NN) return;
  float ad2 = node2[node].w;
  int beg = rowptr[node], end = rowptr[node + 1];
  float den = 0.f, a0 = 0.f, a1 = 0.f;
  for (int j = beg + sub; j < end; j += 4) {
    int s = col[j];
    float4 sv = node2[s];
    float e = sv.z + ad2;
    e = (e < 0.f) ? 0.2f * e : e;
    float w = __expf(fminf(e, 80.f));
    den += w;
    a0 += w * sv.x;
    a1 += w * sv.y;
  }
#pragma unroll
  for (int d = 1; d < 4; d <<= 1) {
    den += __shfl_xor(den, d, 64);
    a0 += __shfl_xor(a0, d, 64);
    a1 += __shfl_xor(a1, d, 64);
  }
  if (sub == 0) {
    float inv = 1.f / (den + 1e-16f);
    float o0 = a0 * inv + b2[0];
    float o1 = a1 * inv + b2[1];
    float m = fmaxf(o0, o1);
    float lse = m + __logf(__expf(o0 - m) + __expf(o1 - m));
    out[node] = make_float2(o0 - lse, o1 - lse);
  }
}

extern "C" void kernel_launch(void* const* d_in, const int* in_sizes, int n_in,
                              void* d_out, int out_size, void* d_ws, size_t ws_size,
                              hipStream_t stream) {
  const float* x     = (const float*)d_in[0];
  const int*   ei    = (const int*)d_in[1];
  const float* W1    = (const float*)d_in[2];
  const float* asrc1 = (const float*)d_in[3];
  const float* adst1 = (const float*)d_in[4];
  const float* b1    = (const float*)d_in[5];
  const float* W2    = (const float*)d_in[6];
  const float* asrc2 = (const float*)d_in[7];
  const float* adst2 = (const float*)d_in[8];
  const float* b2    = (const float*)d_in[9];
  float2* out = (float2*)d_out;

  int* rowptr     = (int*)d_ws;                    // 100352
  int* col        = rowptr + 100352;               // 1700096
  int* pair       = col + 1700096;                 // 1600000
  int* cntMat     = pair + 1600000;                // NCH*NB = 305762, pad 305792
  int* bucketCnt  = cntMat + 305792;               // 1024
  int* pairOffset = bucketCnt + 1024;              // 1024
  unsigned short* h1b = (unsigned short*)(pairOffset + 1024);  // NN*128 bf16
  float*  as1  = (float*)(h1b + (size_t)NN * 128); // NN*4
  float*  ad1  = as1 + NN * 4;                     // NN*4
  float4* node2 = (float4*)(ad1 + NN * 4);         // NN
  unsigned short* W1h = (unsigned short*)(node2 + NN);  // 16384
  unsigned short* W1l = W1h + 16384;                    // 16384

  kb_hist<<<NCH, 512, 0, stream>>>(ei, cntMat);
  kb_colscan<<<NB, 64, 0, stream>>>(cntMat, bucketCnt);
  kb_scan<<<1, 64, 0, stream>>>(bucketCnt, pairOffset);
  kb_scatA<<<NCH, 512, 0, stream>>>(ei, pairOffset, cntMat, pair);
  kb_binB<<<NB, 256, 0, stream>>>(pair, pairOffset, rowptr, col);
  k_cvtW<<<64, 256, 0, stream>>>(W1, W1h, W1l);
  k_gemm1<<<(NN / 16 + 3) / 4, 256, 0, stream>>>(x, W1h, W1l, asrc1, adst1, h1b,
                                                 (float4*)as1, (float4*)ad1);
  k_agg1<<<NN / 16, 256, 0, stream>>>(h1b, as1, ad1, rowptr, col, b1, W2, asrc2, adst2, node2);
  k_agg2<<<(NN * 4 + 255) / 256, 256, 0, stream>>>(node2, rowptr, col, b2, out);
}